// Round 8
// baseline (549.733 us; speedup 1.0000x reference)
//
#include <hip/hip_runtime.h>
#include <math.h>

// Problem constants
#define S_LEN 2048
#define DMODEL 512
#define NROWS 4096   // B*S
#define NHEAD 8
#define HDIM 64
#define LOG2E 1.4426950408889634f

typedef __attribute__((ext_vector_type(8))) __bf16 bf16x8;
typedef __attribute__((ext_vector_type(4))) float f32x4;

__device__ inline float bf2f(unsigned short h) {
    unsigned u = ((unsigned)h) << 16;
    return __builtin_bit_cast(float, u);
}
__device__ inline unsigned short f2bf(float f) {
    unsigned u = __builtin_bit_cast(unsigned, f);
    return (unsigned short)((u + 0x7fffu + ((u >> 16) & 1u)) >> 16);
}

// async global->LDS, 16B per lane; LDS dest = wave-uniform base + lane*16
__device__ inline void gl_lds16(const unsigned short* g, unsigned short* l) {
    __builtin_amdgcn_global_load_lds(
        (const __attribute__((address_space(1))) void*)g,
        (__attribute__((address_space(3))) void*)l, 16, 0, 0);
}

// ---------------- ALL weight prep in ONE launch --------------------------
__global__ __launch_bounds__(256) void prep_all(
    const float* g_wq, const float* g_wk, const float* g_wv, const float* g_wo,
    const float* e_wq, const float* e_wk, const float* e_wv, const float* e_wo,
    const float* e_wf, const float* fg_w1, const float* fe_w1,
    const float* fg_w2, const float* fe_w2,
    const float* g_bq, const float* g_bk, const float* g_bv,
    const float* e_bq, const float* e_bk,
    unsigned short* __restrict__ wbase, float* __restrict__ biasg,
    float* __restrict__ biase)
{
    const int id = blockIdx.x;
    const int tid = threadIdx.x;
    if (id >= 6656) {
        int t = id - 6656;
        if (t < 6) {
            int i = t * 256 + tid;
            biasg[i] = (i < 512) ? g_bq[i] : (i < 1024) ? g_bk[i - 512] : g_bv[i - 1024];
        } else {
            int i = (t - 6) * 256 + tid;
            biase[i] = (i < 512) ? e_bq[i] : e_bk[i - 512];
        }
        return;
    }
    const float* W; unsigned short* Wt; int K, Mo, bx, by;
    if (id < 2048) {
        const float* srcs[8] = {g_wq, g_wk, g_wv, g_wo, e_wq, e_wk, e_wv, e_wo};
        int m = id >> 8, t = id & 255;
        W = srcs[m]; Wt = wbase + (size_t)m * 512 * 512; K = 512; Mo = 512;
        bx = (t & 15) * 32; by = (t >> 4) * 32;
    } else if (id < 2560) {
        int t = id - 2048;
        W = e_wf; Wt = wbase + 8 * 512 * 512; K = 1024; Mo = 512;
        bx = (t & 15) * 32; by = (t >> 4) * 32;
    } else if (id < 4608) {
        int t = id - 2560; int which = t >> 10; t &= 1023;
        W = which ? fe_w1 : fg_w1;
        Wt = wbase + 8 * 512 * 512 + 1024 * 512 + (size_t)which * 512 * 2048;
        K = 512; Mo = 2048;
        bx = (t & 63) * 32; by = (t >> 6) * 32;
    } else {
        int t = id - 4608; int which = t >> 10; t &= 1023;
        W = which ? fe_w2 : fg_w2;
        Wt = wbase + 8 * 512 * 512 + 1024 * 512 + 2 * 512 * 2048 + (size_t)which * 2048 * 512;
        K = 2048; Mo = 512;
        bx = (t & 15) * 32; by = (t >> 4) * 32;
    }
    __shared__ float tsh[32][33];
    const int tx = tid & 31, ty = tid >> 5;
    #pragma unroll
    for (int r = 0; r < 4; ++r)
        tsh[ty + 8 * r][tx] = W[(size_t)(by + ty + 8 * r) * Mo + bx + tx];
    __syncthreads();
    #pragma unroll
    for (int r = 0; r < 4; ++r)
        Wt[(size_t)(bx + ty + 8 * r) * K + by + tx] = f2bf(tsh[tx][ty + 8 * r]);
}

// ---------------- fused front LNs: LN(gene)->bufA16, cast(gene)+LN(expr)->bufCat
__global__ __launch_bounds__(256) void ln_front(
    const float* __restrict__ gene, const float* __restrict__ expr,
    const float* __restrict__ gw, const float* __restrict__ gb,
    const float* __restrict__ ew, const float* __restrict__ eb,
    unsigned short* __restrict__ yg,    // [4096][512]
    unsigned short* __restrict__ ycat)  // [4096][1024]
{
    __shared__ float red[16];
    const int row = blockIdx.x, t = threadIdx.x;
    const float* gr = gene + (size_t)row * DMODEL;
    const float* er = expr + (size_t)row * DMODEL;
    float g0 = gr[t], g1 = gr[t + 256];
    float e0 = er[t], e1 = er[t + 256];
    float sg = g0 + g1, sqg = g0 * g0 + g1 * g1;
    float se = e0 + e1, sqe = e0 * e0 + e1 * e1;
    #pragma unroll
    for (int o = 32; o > 0; o >>= 1) {
        sg += __shfl_down(sg, o);  sqg += __shfl_down(sqg, o);
        se += __shfl_down(se, o);  sqe += __shfl_down(sqe, o);
    }
    int wid = t >> 6, lane = t & 63;
    if (lane == 0) {
        red[wid] = sg; red[4 + wid] = sqg; red[8 + wid] = se; red[12 + wid] = sqe;
    }
    __syncthreads();
    float mg  = (red[0] + red[1] + red[2] + red[3]) * (1.0f / 512.0f);
    float qg_ = (red[4] + red[5] + red[6] + red[7]) * (1.0f / 512.0f);
    float me  = (red[8] + red[9] + red[10] + red[11]) * (1.0f / 512.0f);
    float qe_ = (red[12] + red[13] + red[14] + red[15]) * (1.0f / 512.0f);
    float rg = rsqrtf(qg_ - mg * mg + 1e-5f);
    float re = rsqrtf(qe_ - me * me + 1e-5f);
    yg[(size_t)row * 512 + t]         = f2bf((g0 - mg) * rg * gw[t] + gb[t]);
    yg[(size_t)row * 512 + t + 256]   = f2bf((g1 - mg) * rg * gw[t + 256] + gb[t + 256]);
    unsigned short* yr = ycat + (size_t)row * 1024;
    yr[t]             = f2bf(g0);
    yr[t + 256]       = f2bf(g1);
    yr[512 + t]       = f2bf((e0 - me) * re * ew[t] + eb[t]);
    yr[512 + t + 256] = f2bf((e1 - me) * re * ew[t + 256] + eb[t + 256]);
}

// ---------------- LayerNorm: fp32 in, bf16 out (strided) ----------------
__global__ __launch_bounds__(256) void ln_kernel(
    const float* __restrict__ x, const float* __restrict__ w,
    const float* __restrict__ b, unsigned short* __restrict__ y, int ostride)
{
    __shared__ float red[8];
    const int row = blockIdx.x;
    const float* xr = x + (size_t)row * DMODEL;
    const int t = threadIdx.x;
    float v0 = xr[t];
    float v1 = xr[t + 256];
    float s  = v0 + v1;
    float sq = v0 * v0 + v1 * v1;
    #pragma unroll
    for (int o = 32; o > 0; o >>= 1) {
        s  += __shfl_down(s, o);
        sq += __shfl_down(sq, o);
    }
    int wid = t >> 6, lane = t & 63;
    if (lane == 0) { red[wid] = s; red[4 + wid] = sq; }
    __syncthreads();
    float mean = (red[0] + red[1] + red[2] + red[3]) * (1.0f / 512.0f);
    float msq  = (red[4] + red[5] + red[6] + red[7]) * (1.0f / 512.0f);
    float var  = msq - mean * mean;
    float rs   = rsqrtf(var + 1e-5f);
    y[(size_t)row * ostride + t]       = f2bf((v0 - mean) * rs * w[t] + b[t]);
    y[(size_t)row * ostride + t + 256] = f2bf((v1 - mean) * rs * w[t + 256] + b[t + 256]);
}

// ---------------- V transpose: Vt[(b*8+h)*64 + d][s] = V[b*2048+s][h*64+d] --
__global__ __launch_bounds__(256) void vtrans(
    const unsigned short* __restrict__ V, int ldv, unsigned short* __restrict__ Vt)
{
    __shared__ unsigned short t[64][72];
    const int s0 = blockIdx.x * 64, h = blockIdx.y, b = blockIdx.z;
    const int tid = threadIdx.x;
    {
        const int r = tid >> 2, c = (tid & 3) * 16;
        const unsigned short* src = V + (size_t)(b * S_LEN + s0 + r) * ldv + h * 64 + c;
        *(int4*)&t[r][c]     = *(const int4*)(src);
        *(int4*)&t[r][c + 8] = *(const int4*)(src + 8);
    }
    __syncthreads();
    {
        const int d = tid >> 2, s = (tid & 3) * 16;
        unsigned short* dst = Vt + ((size_t)((b * 8 + h) * 64 + d)) * S_LEN + s0 + s;
        unsigned short tmp[16];
        #pragma unroll
        for (int e = 0; e < 16; ++e) tmp[e] = t[s + e][d];
        *(int4*)dst       = *(int4*)&tmp[0];
        *(int4*)(dst + 8) = *(int4*)&tmp[8];
    }
}

// ---------------- bf16 MFMA GEMM, 128x128 tile, BK=32, 8 WAVES -----------
// 512 threads; waves as 2x4 over 64x32 sub-tiles (6 ds_read : 8 MFMA,
// acc[4][2]). Double the resident waves of the 4-wave version at the same
// grid -> 2x latency hiding (the measured binding resource). Depth-2
// pipeline, counted vmcnt(2) (2 loads/thread/stage, 2 tiles in flight).
__global__ __launch_bounds__(512) void gemm_mfma(
    const unsigned short* __restrict__ A, int lda,
    const unsigned short* __restrict__ Bt,
    const float* __restrict__ bias,
    const float* __restrict__ R1,
    const unsigned short* __restrict__ R2,
    float* __restrict__ Cf, unsigned short* __restrict__ Cb,
    int K, int Mo, int dogelu)
{
    __shared__ __align__(16) unsigned short As[3][128 * 32];
    __shared__ __align__(16) unsigned short Bs[3][128 * 32];
    const int tid = threadIdx.x;
    const int wave = tid >> 6, lane = tid & 63;
    const int wr = wave >> 2, wc = wave & 3;       // 2x4 wave grid
    const int row0 = blockIdx.y * 128, col0 = blockIdx.x * 128;
    const int l15 = lane & 15, q = lane >> 4;

    f32x4 acc[4][2];
    const f32x4 zz = {0.f, 0.f, 0.f, 0.f};
    #pragma unroll
    for (int i = 0; i < 4; ++i)
        #pragma unroll
        for (int j = 0; j < 2; ++j) acc[i][j] = zz;

    const int nk = K >> 5;
    auto stage = [&](int t, int buf) {
        const int k0 = t * 32;
        const int row = tid >> 2, kc = tid & 3;    // 512 threads cover 128x4
        gl_lds16(&A[(size_t)(row0 + row) * lda + k0 + kc * 8],
                 &As[buf][(size_t)(wave * 64) * 8]);
        gl_lds16(&Bt[(size_t)(col0 + row) * K + k0 + kc * 8],
                 &Bs[buf][(size_t)(wave * 64) * 8]);
    };
    stage(0, 0);
    if (nk > 1) stage(1, 1);

    int cur = 0, nx2 = 2;
    for (int t = 0; t < nk; ++t) {
        if (t + 1 < nk) asm volatile("s_waitcnt vmcnt(2)" ::: "memory");
        else            asm volatile("s_waitcnt vmcnt(0)" ::: "memory");
        __builtin_amdgcn_s_barrier();
        if (t + 2 < nk) stage(t + 2, nx2);

        bf16x8 af[4], bfr[2];
        #pragma unroll
        for (int fi = 0; fi < 4; ++fi)
            af[fi] = *(const bf16x8*)&As[cur][(wr * 64 + fi * 16 + l15) * 32 + q * 8];
        #pragma unroll
        for (int fj = 0; fj < 2; ++fj)
            bfr[fj] = *(const bf16x8*)&Bs[cur][(wc * 32 + fj * 16 + l15) * 32 + q * 8];
        #pragma unroll
        for (int fi = 0; fi < 4; ++fi)
            #pragma unroll
            for (int fj = 0; fj < 2; ++fj)
                acc[fi][fj] = __builtin_amdgcn_mfma_f32_16x16x32_bf16(
                    af[fi], bfr[fj], acc[fi][fj], 0, 0, 0);

        cur = (cur == 2) ? 0 : cur + 1;
        nx2 = (nx2 == 2) ? 0 : nx2 + 1;
    }

    #pragma unroll
    for (int fi = 0; fi < 4; ++fi) {
        #pragma unroll
        for (int reg = 0; reg < 4; ++reg) {
            int row = row0 + wr * 64 + fi * 16 + q * 4 + reg;
            #pragma unroll
            for (int fj = 0; fj < 2; ++fj) {
                int col = col0 + wc * 32 + fj * 16 + l15;
                float v = acc[fi][fj][reg] + bias[col];
                if (dogelu) v = 0.5f * v * (1.0f + erff(v * 0.70710678118654752f));
                size_t off = (size_t)row * Mo + col;
                if (R1) v += R1[off];
                if (R2) v += bf2f(R2[off]);
                if (Cb) Cb[off] = f2bf(v);
                else    Cf[off] = v;
            }
        }
    }
}

// ---------------- bf16 MFMA GEMM, 64x64 tile, BK=64 (unchanged) ----------
__global__ __launch_bounds__(256) void gemm_mfma64(
    const unsigned short* __restrict__ A, int lda,
    const unsigned short* __restrict__ Bt,
    const float* __restrict__ bias,
    const float* __restrict__ R1,
    const unsigned short* __restrict__ R2,
    float* __restrict__ Cf, unsigned short* __restrict__ Cb,
    int K, int Mo, int dogelu)
{
    __shared__ __align__(16) unsigned short As[3][64 * 64];
    __shared__ __align__(16) unsigned short Bs[3][64 * 64];
    const int tid = threadIdx.x;
    const int wave = tid >> 6, lane = tid & 63;
    const int row0 = blockIdx.y * 64, col0 = blockIdx.x * 64;
    const int l15 = lane & 15, q = lane >> 4;

    f32x4 acc[4];
    const f32x4 zz = {0.f, 0.f, 0.f, 0.f};
    #pragma unroll
    for (int j = 0; j < 4; ++j) acc[j] = zz;

    const int nk = K >> 6;
    auto stage = [&](int t, int buf) {
        const int k0 = t * 64;
        #pragma unroll
        for (int r = 0; r < 2; ++r) {
            int idx = r * 256 + tid;
            int row = idx >> 3;
            int kc  = (idx & 7) ^ (row & 7);
            gl_lds16(&A[(size_t)(row0 + row) * lda + k0 + kc * 8],
                     &As[buf][(size_t)(r * 256 + wave * 64) * 8]);
            gl_lds16(&Bt[(size_t)(col0 + row) * K + k0 + kc * 8],
                     &Bs[buf][(size_t)(r * 256 + wave * 64) * 8]);
        }
    };
    stage(0, 0);
    if (nk > 1) stage(1, 1);

    int cur = 0, nx2 = 2;
    for (int t = 0; t < nk; ++t) {
        if (t + 1 < nk) asm volatile("s_waitcnt vmcnt(4)" ::: "memory");
        else            asm volatile("s_waitcnt vmcnt(0)" ::: "memory");
        __builtin_amdgcn_s_barrier();
        if (t + 2 < nk) stage(t + 2, nx2);

        #pragma unroll
        for (int ks = 0; ks < 2; ++ks) {
            const int cx = ((ks * 4 + q) ^ (l15 & 7)) * 8;   // swizzled chunk
            bf16x8 af = *(const bf16x8*)&As[cur][(wave * 16 + l15) * 64 + cx];
            bf16x8 bfr[4];
            #pragma unroll
            for (int fj = 0; fj < 4; ++fj)
                bfr[fj] = *(const bf16x8*)&Bs[cur][(fj * 16 + l15) * 64 + cx];
            #pragma unroll
            for (int fj = 0; fj < 4; ++fj)
                acc[fj] = __builtin_amdgcn_mfma_f32_16x16x32_bf16(af, bfr[fj], acc[fj], 0, 0, 0);
        }

        cur = (cur == 2) ? 0 : cur + 1;
        nx2 = (nx2 == 2) ? 0 : nx2 + 1;
    }

    #pragma unroll
    for (int reg = 0; reg < 4; ++reg) {
        int row = row0 + wave * 16 + q * 4 + reg;
        #pragma unroll
        for (int fj = 0; fj < 4; ++fj) {
            int col = col0 + fj * 16 + l15;
            float v = acc[fj][reg] + bias[col];
            if (dogelu) v = 0.5f * v * (1.0f + erff(v * 0.70710678118654752f));
            size_t off = (size_t)row * Mo + col;
            if (R1) v += R1[off];
            if (R2) v += bf2f(R2[off]);
            if (Cb) Cb[off] = f2bf(v);
            else    Cf[off] = v;
        }
    }
}

// ---------------- MFMA flash attention, 8-wave, in-block KV-split x2 ------
// 512 threads = 2 groups x 4 waves. Group g runs online-softmax attention
// over KV half [g*1024, g*1024+1024) for the SAME 64 q-rows (exactly the
// old split-K halves), each with its own K/V LDS double-stage. At the end
// the two groups' (m, Z, Zm, O) are merged IN LDS (same algebra as the old
// combine kernel) and group 0 writes final O. Doubles resident waves
// (8 -> 16 per CU) without partial buffers or combine dispatches.
__global__ __launch_bounds__(512, 4) void attn_mfma(
    const unsigned short* __restrict__ Q, int ldq,
    const unsigned short* __restrict__ Kp, int ldk,
    const unsigned short* __restrict__ Vt,   // [16 bh][64 d][2048 s]
    const float* __restrict__ M,
    unsigned short* __restrict__ O)          // [4096][512] bf16
{
    // layout (shorts): Ks0[4608] Vs0[4608] Ks1[4608] Vs1[4608] Ps[8][1152]
    __shared__ __align__(16) unsigned short smem[27648];

    const int tid = threadIdx.x;
    const int grp = tid >> 8;            // 0,1
    const int gtid = tid & 255;
    const int wave = tid >> 6;           // 0..7
    const int wrow = wave & 3;           // q-row wave within group
    const int lane = tid & 63;
    const int l15 = lane & 15, quad = lane >> 4;
    const int bh = blockIdx.y, b = bh >> 3, h = bh & 7;
    const int q0 = blockIdx.x * 64;
    const int iRow = q0 + wrow * 16 + l15;
    const int kBeg = grp * (S_LEN / 2), kEnd = kBeg + (S_LEN / 2);

    unsigned short* Ks = smem + grp * 9216;
    unsigned short* Vs = Ks + 4608;
    unsigned short* Ps = smem + 18432 + wave * 1152;   // [16][72] shorts

    // Q fragments, pre-scaled into log2 domain (both groups load same rows)
    bf16x8 qf[2];
    {
        const unsigned short* qp = Q + (size_t)(b * S_LEN + iRow) * ldq + h * HDIM + quad * 8;
        #pragma unroll
        for (int ks = 0; ks < 2; ++ks) {
            union { bf16x8 v; unsigned short u[8]; } tq;
            tq.v = *(const bf16x8*)(qp + ks * 32);
            #pragma unroll
            for (int e = 0; e < 8; ++e)
                tq.u[e] = f2bf(bf2f(tq.u[e]) * (0.125f * LOG2E));
            qf[ks] = tq.v;
        }
    }

    // group-local coalesced staging addresses
    const int srow = gtid >> 3;           // 0..31
    const int scol = (gtid & 7) * 8;      // 0..56 shorts
    const unsigned short* kg = Kp + ((size_t)b * S_LEN) * ldk + h * HDIM + scol;
    const unsigned short* vg = Vt + ((size_t)bh * 64 + srow) * S_LEN + scol;
    const float* mrow = M + ((size_t)b * S_LEN + iRow) * S_LEN + quad * 4;

    float rm = -INFINITY, rZ = 0.f, rZm = 0.f;   // per-lane partials
    f32x4 oacc[4];
    const f32x4 zz = {0.f, 0.f, 0.f, 0.f};
    #pragma unroll
    for (int dt = 0; dt < 4; ++dt) oacc[dt] = zz;

    // prologue: stage first tile of this group's KV half + first M frags
    int4 kv0 = *(const int4*)(kg + (size_t)(kBeg + srow) * ldk);
    int4 kv1 = *(const int4*)(kg + (size_t)(kBeg + srow + 32) * ldk);
    int4 vv0 = *(const int4*)(vg + kBeg);
    int4 vv1 = *(const int4*)(vg + 32 * S_LEN + kBeg);
    float4 m4[4], m4n[4];
    #pragma unroll
    for (int jt = 0; jt < 4; ++jt)
        m4[jt] = *(const float4*)(mrow + kBeg + jt * 16);
    *(int4*)&Ks[srow * 72 + scol]        = kv0;
    *(int4*)&Ks[(srow + 32) * 72 + scol] = kv1;
    *(int4*)&Vs[srow * 72 + scol]        = vv0;
    *(int4*)&Vs[(srow + 32) * 72 + scol] = vv1;
    __syncthreads();

    for (int k0 = kBeg; k0 < kEnd; k0 += 64) {
        const bool more = (k0 + 64 < kEnd);
        // T14: issue next tile's K/V AND M loads; latency hides under compute
        if (more) {
            kv0 = *(const int4*)(kg + (size_t)(k0 + 64 + srow) * ldk);
            kv1 = *(const int4*)(kg + (size_t)(k0 + 64 + srow + 32) * ldk);
            vv0 = *(const int4*)(vg + k0 + 64);
            vv1 = *(const int4*)(vg + 32 * S_LEN + k0 + 64);
            #pragma unroll
            for (int jt = 0; jt < 4; ++jt)
                m4n[jt] = *(const float4*)(mrow + k0 + 64 + jt * 16);
        }

        // QK^T from LDS K
        f32x4 sacc[4];
        #pragma unroll
        for (int jt = 0; jt < 4; ++jt) sacc[jt] = zz;
        __builtin_amdgcn_s_setprio(1);
        #pragma unroll
        for (int jt = 0; jt < 4; ++jt) {
            bf16x8 kf0 = *(const bf16x8*)&Ks[(jt * 16 + l15) * 72 + quad * 8];
            bf16x8 kf1 = *(const bf16x8*)&Ks[(jt * 16 + l15) * 72 + 32 + quad * 8];
            sacc[jt] = __builtin_amdgcn_mfma_f32_16x16x32_bf16(kf0, qf[0], sacc[jt], 0, 0, 0);
            sacc[jt] = __builtin_amdgcn_mfma_f32_16x16x32_bf16(kf1, qf[1], sacc[jt], 0, 0, 0);
        }
        __builtin_amdgcn_s_setprio(0);

        // masked scores + tree row-max (log2 domain)
        float mxj[4];
        #pragma unroll
        for (int jt = 0; jt < 4; ++jt) {
            float mm[4] = {m4[jt].x, m4[jt].y, m4[jt].z, m4[jt].w};
            #pragma unroll
            for (int r = 0; r < 4; ++r)
                sacc[jt][r] = sacc[jt][r] * mm[r];
            mxj[jt] = fmaxf(fmaxf(sacc[jt][0], sacc[jt][1]),
                            fmaxf(sacc[jt][2], sacc[jt][3]));
        }
        float mx = fmaxf(fmaxf(mxj[0], mxj[1]), fmaxf(mxj[2], mxj[3]));
        mx = fmaxf(mx, __shfl_xor(mx, 16));
        mx = fmaxf(mx, __shfl_xor(mx, 32));
        // T13 defer-max
        if (!__all(mx <= rm + 8.0f)) {
            float mn = fmaxf(rm, mx);
            float al = __builtin_amdgcn_exp2f(rm - mn);
            rm = mn; rZ *= al; rZm *= al;
            #pragma unroll
            for (int dt = 0; dt < 4; ++dt)
                #pragma unroll
                for (int r = 0; r < 4; ++r) oacc[dt][r] *= al;
        }

        // P = exp2(s - rm); per-lane z/zm accumulation
        float z = 0.f, zm = 0.f;
        #pragma unroll
        for (int jt = 0; jt < 4; ++jt) {
            float mm[4] = {m4[jt].x, m4[jt].y, m4[jt].z, m4[jt].w};
            float pv[4];
            #pragma unroll
            for (int r = 0; r < 4; ++r) {
                float e = __builtin_amdgcn_exp2f(sacc[jt][r] - rm);
                float pm = e * mm[r];
                z += e; zm += pm; pv[r] = pm;
            }
            unsigned lo, hi;
            asm("v_cvt_pk_bf16_f32 %0, %1, %2" : "=v"(lo) : "v"(pv[0]), "v"(pv[1]));
            asm("v_cvt_pk_bf16_f32 %0, %1, %2" : "=v"(hi) : "v"(pv[2]), "v"(pv[3]));
            uint2 pk; pk.x = lo; pk.y = hi;
            *(uint2*)&Ps[l15 * 72 + jt * 16 + quad * 4] = pk;
        }
        rZ += z; rZm += zm;

        // PV from LDS V; P from per-wave LDS
        bf16x8 pf0 = *(const bf16x8*)&Ps[l15 * 72 + quad * 8];
        bf16x8 pf1 = *(const bf16x8*)&Ps[l15 * 72 + 32 + quad * 8];
        __builtin_amdgcn_s_setprio(1);
        #pragma unroll
        for (int dt = 0; dt < 4; ++dt) {
            bf16x8 vf0 = *(const bf16x8*)&Vs[(dt * 16 + l15) * 72 + quad * 8];
            bf16x8 vf1 = *(const bf16x8*)&Vs[(dt * 16 + l15) * 72 + 32 + quad * 8];
            oacc[dt] = __builtin_amdgcn_mfma_f32_16x16x32_bf16(vf0, pf0, oacc[dt], 0, 0, 0);
            oacc[dt] = __builtin_amdgcn_mfma_f32_16x16x32_bf16(vf1, pf1, oacc[dt], 0, 0, 0);
        }
        __builtin_amdgcn_s_setprio(0);

        // commit prefetched tile to LDS; roll M fragments
        if (more) {
            __syncthreads();
            *(int4*)&Ks[srow * 72 + scol]        = kv0;
            *(int4*)&Ks[(srow + 32) * 72 + scol] = kv1;
            *(int4*)&Vs[srow * 72 + scol]        = vv0;
            *(int4*)&Vs[(srow + 32) * 72 + scol] = vv1;
            __syncthreads();
            #pragma unroll
            for (int jt = 0; jt < 4; ++jt) m4[jt] = m4n[jt];
        }
    }

    // ---- in-block merge of the two KV halves (combine algebra) ----
    // overlay buffers on Ks0/Vs0/Ks1 region (all staging reads are done):
    //   mO: [256][20] f32 (16 data + 4 pad, bank spread), bytes 0..20480
    //   mS: [256][3]  f32, bytes 20480..23552  (< Ps at 36864)
    __syncthreads();
    float* mO = (float*)smem;
    float* mS = (float*)((char*)smem + 20480);
    if (grp == 1) {
        #pragma unroll
        for (int dt = 0; dt < 4; ++dt)
            *(f32x4*)&mO[gtid * 20 + dt * 4] = oacc[dt];
        mS[gtid * 3 + 0] = rm;
        mS[gtid * 3 + 1] = rZ;
        mS[gtid * 3 + 2] = rZm;
    }
    __syncthreads();
    if (grp == 0) {
        float rm1 = mS[gtid * 3 + 0], rZ1 = mS[gtid * 3 + 1], rZm1 = mS[gtid * 3 + 2];
        float mstar = fmaxf(rm, rm1);
        float a0 = __builtin_amdgcn_exp2f(rm - mstar);
        float a1 = __builtin_amdgcn_exp2f(rm1 - mstar);
        rZ  = rZ * a0 + rZ1 * a1;
        rZm = rZm * a0 + rZm1 * a1;
        #pragma unroll
        for (int dt = 0; dt < 4; ++dt) {
            f32x4 o1 = *(const f32x4*)&mO[gtid * 20 + dt * 4];
            #pragma unroll
            for (int r = 0; r < 4; ++r)
                oacc[dt][r] = oacc[dt][r] * a0 + o1[r] * a1;
        }
        // deferred cross-lane reduction, normalize, write final O
        rZ  += __shfl_xor(rZ, 16);  rZ  += __shfl_xor(rZ, 32);
        rZm += __shfl_xor(rZm, 16); rZm += __shfl_xor(rZm, 32);
        float inv = 1.0f / (rZm + 1e-8f * rZ);

        unsigned short* op = O + (size_t)(b * S_LEN + iRow) * DMODEL + h * HDIM;
        #pragma unroll
        for (int dt = 0; dt < 4; ++dt) {
            float o0 = oacc[dt][0] * inv, o1 = oacc[dt][1] * inv;
            float o2 = oacc[dt][2] * inv, o3 = oacc[dt][3] * inv;
            unsigned lo, hi;
            asm("v_cvt_pk_bf16_f32 %0, %1, %2" : "=v"(lo) : "v"(o0), "v"(o1));
            asm("v_cvt_pk_bf16_f32 %0, %1, %2" : "=v"(hi) : "v"(o2), "v"(o3));
            uint2 o2v; o2v.x = lo; o2v.y = hi;
            *(uint2*)(op + dt * 16 + quad * 4) = o2v;
        }
    }
}

// ---------------- launch ----------------
extern "C" void kernel_launch(void* const* d_in, const int* in_sizes, int n_in,
                              void* d_out, int out_size, void* d_ws, size_t ws_size,
                              hipStream_t stream)
{
    const float* gene_emb = (const float*)d_in[0];
    const float* expr_emb = (const float*)d_in[1];
    const float* M        = (const float*)d_in[2];
    const float* g_wq = (const float*)d_in[3];
    const float* g_wk = (const float*)d_in[4];
    const float* g_wv = (const float*)d_in[5];
    const float* g_wo = (const float*)d_in[6];
    const float* g_bq = (const float*)d_in[7];
    const float* g_bk = (const float*)d_in[8];
    const float* g_bv = (const float*)d_in[9];
    const float* g_bo = (const float*)d_in[10];
    const float* e_wf = (const float*)d_in[11];
    const float* e_bf = (const float*)d_in[12];
    const float* e_wq = (const float*)d_in[13];
    const float* e_wk = (const float*)d_in[14];
    const float* e_wv = (const float*)d_in[15];
    const float* e_wo = (const float*)d_in[16];
    const float* e_bq = (const float*)d_in[17];
    const float* e_bk = (const float*)d_in[18];
    const float* e_bv = (const float*)d_in[19];
    const float* e_bo = (const float*)d_in[20];
    const float* ln_g1_w = (const float*)d_in[21];
    const float* ln_g2_w = (const float*)d_in[22];
    const float* ln_e1_w = (const float*)d_in[23];
    const float* ln_e2_w = (const float*)d_in[24];
    const float* ln_g1_b = (const float*)d_in[25];
    const float* ln_g2_b = (const float*)d_in[26];
    const float* ln_e1_b = (const float*)d_in[27];
    const float* ln_e2_b = (const float*)d_in[28];
    const float* fg_w1 = (const float*)d_in[29];
    const float* fg_b1 = (const float*)d_in[30];
    const float* fg_w2 = (const float*)d_in[31];
    const float* fg_b2 = (const float*)d_in[32];
    const float* fe_w1 = (const float*)d_in[33];
    const float* fe_b1 = (const float*)d_in[34];
    const float* fe_w2 = (const float*)d_in[35];
    const float* fe_b2 = (const float*)d_in[36];

    float* out_gene = (float*)d_out;
    float* out_expr = out_gene + (size_t)NROWS * DMODEL;

    // ---- workspace (MB offsets) ----
    char* ws = (char*)d_ws;
    const size_t MB1 = 1024 * 1024;
    unsigned short* bufA16  = (unsigned short*)(ws + 0 * MB1);   // 0-4
    unsigned short* bufAt16 = (unsigned short*)(ws + 4 * MB1);   // 4-8 attn out
    unsigned short* bufQKV  = (unsigned short*)(ws + 8 * MB1);   // 8-20 gene [4096][1536]
    unsigned short* bufQKe  = (unsigned short*)(ws + 8 * MB1);   // 8-16 expr [4096][1024]
    unsigned short* bufV16  = (unsigned short*)(ws + 16 * MB1);  // 16-20 expr V
    unsigned short* bufVt   = (unsigned short*)(ws + 20 * MB1);  // 20-24
    unsigned short* bufCat  = (unsigned short*)(ws + 24 * MB1);  // 24-32 expr concat
    float*          bufX    = (float*)(ws + 33 * MB1);           // 33-41 fp32 residual
    unsigned short* bufH16  = (unsigned short*)(ws + 8 * MB1);   // 8-24 FFN hidden
    char* wp = ws + 41 * MB1;
    unsigned short* sq8    = (unsigned short*)wp;                 // 8 x 512x512
    unsigned short* gwq_t  = sq8 + 0 * 512 * 512;
    unsigned short* gwo_t  = sq8 + 3 * 512 * 512;
    unsigned short* ewq_t  = sq8 + 4 * 512 * 512;
    unsigned short* ewv_t  = sq8 + 6 * 512 * 512;
    unsigned short* ewo_t  = sq8 + 7 * 512 * 512;
    unsigned short* ewf_t  = sq8 + 8 * 512 * 512;                 // 1024x512
    unsigned short* ffn1   = ewf_t + 1024 * 512;                  // 2 x [2048][512]
    unsigned short* fgw1_t = ffn1;
    unsigned short* few1_t = ffn1 + 512 * 2048;
    unsigned short* ffn2   = few1_t + 512 * 2048;                 // 2 x [512][2048]
    unsigned short* fgw2_t = ffn2;
    unsigned short* few2_t = ffn2 + 2048 * 512;
    float* biasg = (float*)(few2_t + 2048 * 512);
    float* biase = biasg + 1536;

    dim3 blk(256);
    dim3 blk512(512);
    dim3 ln_grid(NROWS);
    dim3 g512s(8, 64);    // 64x64 tiles, Mo=512 -> 512 blocks
    dim3 g1024(8, 32);
    dim3 g1536(12, 32);
    dim3 g2048(16, 32);
    dim3 attn_grid(S_LEN / 64, 16);
    dim3 vt_grid(S_LEN / 64, NHEAD, 2);

    // ---- ALL weight prep: one launch ----
    prep_all<<<dim3(6666), blk, 0, stream>>>(
        g_wq, g_wk, g_wv, g_wo, e_wq, e_wk, e_wv, e_wo,
        e_wf, fg_w1, fe_w1, fg_w2, fe_w2,
        g_bq, g_bk, g_bv, e_bq, e_bk,
        sq8, biasg, biase);

    // ---- fused front LNs ----
    ln_front<<<ln_grid, blk, 0, stream>>>(
        gene_emb, expr_emb, ln_g1_w, ln_g1_b, ln_e1_w, ln_e1_b, bufA16, bufCat);

    // ---------------- gene branch ----------------
    gemm_mfma<<<g1536, blk512, 0, stream>>>(bufA16, 512, gwq_t, biasg, nullptr, nullptr, nullptr, bufQKV, 512, 1536, 0);
    vtrans<<<vt_grid, blk, 0, stream>>>(bufQKV + 1024, 1536, bufVt);
    attn_mfma<<<attn_grid, blk512, 0, stream>>>(bufQKV, 1536, bufQKV + 512, 1536, bufVt, M, bufAt16);
    gemm_mfma64<<<g512s, blk, 0, stream>>>(bufAt16, 512, gwo_t, g_bo, gene_emb, nullptr, bufX, nullptr, 512, 512, 0);
    ln_kernel<<<ln_grid, blk, 0, stream>>>(bufX, ln_g2_w, ln_g2_b, bufA16, 512);
    gemm_mfma<<<g2048, blk512, 0, stream>>>(bufA16, 512, fgw1_t, fg_b1, nullptr, nullptr, nullptr, bufH16, 512, 2048, 1);
    gemm_mfma64<<<g512s, blk, 0, stream>>>(bufH16, 2048, fgw2_t, fg_b2, bufX, bufA16, out_gene, nullptr, 2048, 512, 0);

    // ---------------- expr branch ----------------
    gemm_mfma64<<<g512s, blk, 0, stream>>>(bufCat, 1024, ewf_t, e_bf, nullptr, nullptr, nullptr, bufA16, 1024, 512, 0);
    gemm_mfma<<<g1024, blk512, 0, stream>>>(bufA16, 512, ewq_t, biase, nullptr, nullptr, nullptr, bufQKe, 512, 1024, 0);
    gemm_mfma64<<<g512s, blk, 0, stream>>>(bufCat + 512, 1024, ewv_t, e_bv, nullptr, nullptr, nullptr, bufV16, 512, 512, 0);
    vtrans<<<vt_grid, blk, 0, stream>>>(bufV16, 512, bufVt);
    attn_mfma<<<attn_grid, blk512, 0, stream>>>(bufQKe, 1024, bufQKe + 512, 1024, bufVt, M, bufAt16);
    gemm_mfma64<<<g512s, blk, 0, stream>>>(bufAt16, 512, ewo_t, e_bo, expr_emb, nullptr, bufX, nullptr, 512, 512, 0);
    ln_kernel<<<ln_grid, blk, 0, stream>>>(bufX, ln_e2_w, ln_e2_b, bufA16, 512);
    gemm_mfma<<<g2048, blk512, 0, stream>>>(bufA16, 512, few1_t, fe_b1, nullptr, nullptr, nullptr, bufH16, 512, 2048, 1);
    gemm_mfma64<<<g512s, blk, 0, stream>>>(bufH16, 2048, few2_t, fe_b2, bufX, bufA16, out_expr, nullptr, 2048, 512, 0);
}

// Round 9
// 497.328 us; speedup vs baseline: 1.1054x; 1.1054x over previous
//
#include <hip/hip_runtime.h>
#include <math.h>

// Problem constants
#define S_LEN 2048
#define DMODEL 512
#define NROWS 4096   // B*S
#define NHEAD 8
#define HDIM 64
#define LOG2E 1.4426950408889634f

typedef __attribute__((ext_vector_type(8))) __bf16 bf16x8;
typedef __attribute__((ext_vector_type(4))) float f32x4;

__device__ inline float bf2f(unsigned short h) {
    unsigned u = ((unsigned)h) << 16;
    return __builtin_bit_cast(float, u);
}
__device__ inline unsigned short f2bf(float f) {
    unsigned u = __builtin_bit_cast(unsigned, f);
    return (unsigned short)((u + 0x7fffu + ((u >> 16) & 1u)) >> 16);
}

// async global->LDS, 16B per lane; LDS dest = wave-uniform base + lane*16
__device__ inline void gl_lds16(const unsigned short* g, unsigned short* l) {
    __builtin_amdgcn_global_load_lds(
        (const __attribute__((address_space(1))) void*)g,
        (__attribute__((address_space(3))) void*)l, 16, 0, 0);
}

// ---------------- ALL weight prep in ONE launch --------------------------
__global__ __launch_bounds__(256) void prep_all(
    const float* g_wq, const float* g_wk, const float* g_wv, const float* g_wo,
    const float* e_wq, const float* e_wk, const float* e_wv, const float* e_wo,
    const float* e_wf, const float* fg_w1, const float* fe_w1,
    const float* fg_w2, const float* fe_w2,
    const float* g_bq, const float* g_bk, const float* g_bv,
    const float* e_bq, const float* e_bk,
    unsigned short* __restrict__ wbase, float* __restrict__ biasg,
    float* __restrict__ biase)
{
    const int id = blockIdx.x;
    const int tid = threadIdx.x;
    if (id >= 6656) {
        int t = id - 6656;
        if (t < 6) {
            int i = t * 256 + tid;
            biasg[i] = (i < 512) ? g_bq[i] : (i < 1024) ? g_bk[i - 512] : g_bv[i - 1024];
        } else {
            int i = (t - 6) * 256 + tid;
            biase[i] = (i < 512) ? e_bq[i] : e_bk[i - 512];
        }
        return;
    }
    const float* W; unsigned short* Wt; int K, Mo, bx, by;
    if (id < 2048) {
        const float* srcs[8] = {g_wq, g_wk, g_wv, g_wo, e_wq, e_wk, e_wv, e_wo};
        int m = id >> 8, t = id & 255;
        W = srcs[m]; Wt = wbase + (size_t)m * 512 * 512; K = 512; Mo = 512;
        bx = (t & 15) * 32; by = (t >> 4) * 32;
    } else if (id < 2560) {
        int t = id - 2048;
        W = e_wf; Wt = wbase + 8 * 512 * 512; K = 1024; Mo = 512;
        bx = (t & 15) * 32; by = (t >> 4) * 32;
    } else if (id < 4608) {
        int t = id - 2560; int which = t >> 10; t &= 1023;
        W = which ? fe_w1 : fg_w1;
        Wt = wbase + 8 * 512 * 512 + 1024 * 512 + (size_t)which * 512 * 2048;
        K = 512; Mo = 2048;
        bx = (t & 63) * 32; by = (t >> 6) * 32;
    } else {
        int t = id - 4608; int which = t >> 10; t &= 1023;
        W = which ? fe_w2 : fg_w2;
        Wt = wbase + 8 * 512 * 512 + 1024 * 512 + 2 * 512 * 2048 + (size_t)which * 2048 * 512;
        K = 2048; Mo = 512;
        bx = (t & 15) * 32; by = (t >> 4) * 32;
    }
    __shared__ float tsh[32][33];
    const int tx = tid & 31, ty = tid >> 5;
    #pragma unroll
    for (int r = 0; r < 4; ++r)
        tsh[ty + 8 * r][tx] = W[(size_t)(by + ty + 8 * r) * Mo + bx + tx];
    __syncthreads();
    #pragma unroll
    for (int r = 0; r < 4; ++r)
        Wt[(size_t)(bx + ty + 8 * r) * K + by + tx] = f2bf(tsh[tx][ty + 8 * r]);
}

// ---------------- LayerNorm: fp32 in, bf16 out (strided) ----------------
__global__ __launch_bounds__(256) void ln_kernel(
    const float* __restrict__ x, const float* __restrict__ w,
    const float* __restrict__ b, unsigned short* __restrict__ y, int ostride)
{
    __shared__ float red[8];
    const int row = blockIdx.x;
    const float* xr = x + (size_t)row * DMODEL;
    const int t = threadIdx.x;
    float v0 = xr[t];
    float v1 = xr[t + 256];
    float s  = v0 + v1;
    float sq = v0 * v0 + v1 * v1;
    #pragma unroll
    for (int o = 32; o > 0; o >>= 1) {
        s  += __shfl_down(s, o);
        sq += __shfl_down(sq, o);
    }
    int wid = t >> 6, lane = t & 63;
    if (lane == 0) { red[wid] = s; red[4 + wid] = sq; }
    __syncthreads();
    float mean = (red[0] + red[1] + red[2] + red[3]) * (1.0f / 512.0f);
    float msq  = (red[4] + red[5] + red[6] + red[7]) * (1.0f / 512.0f);
    float var  = msq - mean * mean;
    float rs   = rsqrtf(var + 1e-5f);
    y[(size_t)row * ostride + t]       = f2bf((v0 - mean) * rs * w[t] + b[t]);
    y[(size_t)row * ostride + t + 256] = f2bf((v1 - mean) * rs * w[t + 256] + b[t + 256]);
}

// ---------------- fused: cast(gene)->left half, LN(expr)->right half ------
__global__ __launch_bounds__(256) void ln_cat_kernel(
    const float* __restrict__ xg, const float* __restrict__ xe,
    const float* __restrict__ w, const float* __restrict__ b,
    unsigned short* __restrict__ y)   // [4096][1024]
{
    __shared__ float red[8];
    const int row = blockIdx.x;
    const int t = threadIdx.x;
    const float* gr = xg + (size_t)row * DMODEL;
    const float* er = xe + (size_t)row * DMODEL;
    float g0 = gr[t], g1 = gr[t + 256];
    float v0 = er[t], v1 = er[t + 256];
    float s  = v0 + v1;
    float sq = v0 * v0 + v1 * v1;
    #pragma unroll
    for (int o = 32; o > 0; o >>= 1) {
        s  += __shfl_down(s, o);
        sq += __shfl_down(sq, o);
    }
    int wid = t >> 6, lane = t & 63;
    if (lane == 0) { red[wid] = s; red[4 + wid] = sq; }
    __syncthreads();
    float mean = (red[0] + red[1] + red[2] + red[3]) * (1.0f / 512.0f);
    float msq  = (red[4] + red[5] + red[6] + red[7]) * (1.0f / 512.0f);
    float var  = msq - mean * mean;
    float rs   = rsqrtf(var + 1e-5f);
    unsigned short* yr = y + (size_t)row * 1024;
    yr[t]             = f2bf(g0);
    yr[t + 256]       = f2bf(g1);
    yr[512 + t]       = f2bf((v0 - mean) * rs * w[t] + b[t]);
    yr[512 + t + 256] = f2bf((v1 - mean) * rs * w[t + 256] + b[t + 256]);
}

// ---------------- V transpose: Vt[(b*8+h)*64 + d][s] = V[b*2048+s][h*64+d] --
__global__ __launch_bounds__(256) void vtrans(
    const unsigned short* __restrict__ V, int ldv, unsigned short* __restrict__ Vt)
{
    __shared__ unsigned short t[64][72];
    const int s0 = blockIdx.x * 64, h = blockIdx.y, b = blockIdx.z;
    const int tid = threadIdx.x;
    {
        const int r = tid >> 2, c = (tid & 3) * 16;
        const unsigned short* src = V + (size_t)(b * S_LEN + s0 + r) * ldv + h * 64 + c;
        *(int4*)&t[r][c]     = *(const int4*)(src);
        *(int4*)&t[r][c + 8] = *(const int4*)(src + 8);
    }
    __syncthreads();
    {
        const int d = tid >> 2, s = (tid & 3) * 16;
        unsigned short* dst = Vt + ((size_t)((b * 8 + h) * 64 + d)) * S_LEN + s0 + s;
        unsigned short tmp[16];
        #pragma unroll
        for (int e = 0; e < 16; ++e) tmp[e] = t[s + e][d];
        *(int4*)dst       = *(int4*)&tmp[0];
        *(int4*)(dst + 8) = *(int4*)&tmp[8];
    }
}

// ---------------- bf16 MFMA GEMM, 128x128 tile, BK=32, 8 WAVES -----------
// 512 threads; waves as 2x4 over 64x32 sub-tiles. Validated ~+38us on the
// QKV/FFN1 fleet in round 8 (doubles resident waves). Depth-2 pipeline,
// counted vmcnt(2) (2 loads/thread/stage, 2 tiles in flight).
__global__ __launch_bounds__(512) void gemm_mfma(
    const unsigned short* __restrict__ A, int lda,
    const unsigned short* __restrict__ Bt,
    const float* __restrict__ bias,
    const float* __restrict__ R1,
    const unsigned short* __restrict__ R2,
    float* __restrict__ Cf, unsigned short* __restrict__ Cb,
    int K, int Mo, int dogelu)
{
    __shared__ __align__(16) unsigned short As[3][128 * 32];
    __shared__ __align__(16) unsigned short Bs[3][128 * 32];
    const int tid = threadIdx.x;
    const int wave = tid >> 6, lane = tid & 63;
    const int wr = wave >> 2, wc = wave & 3;       // 2x4 wave grid
    const int row0 = blockIdx.y * 128, col0 = blockIdx.x * 128;
    const int l15 = lane & 15, q = lane >> 4;

    f32x4 acc[4][2];
    const f32x4 zz = {0.f, 0.f, 0.f, 0.f};
    #pragma unroll
    for (int i = 0; i < 4; ++i)
        #pragma unroll
        for (int j = 0; j < 2; ++j) acc[i][j] = zz;

    const int nk = K >> 5;
    auto stage = [&](int t, int buf) {
        const int k0 = t * 32;
        const int row = tid >> 2, kc = tid & 3;    // 512 threads cover 128x4
        gl_lds16(&A[(size_t)(row0 + row) * lda + k0 + kc * 8],
                 &As[buf][(size_t)(wave * 64) * 8]);
        gl_lds16(&Bt[(size_t)(col0 + row) * K + k0 + kc * 8],
                 &Bs[buf][(size_t)(wave * 64) * 8]);
    };
    stage(0, 0);
    if (nk > 1) stage(1, 1);

    int cur = 0, nx2 = 2;
    for (int t = 0; t < nk; ++t) {
        if (t + 1 < nk) asm volatile("s_waitcnt vmcnt(2)" ::: "memory");
        else            asm volatile("s_waitcnt vmcnt(0)" ::: "memory");
        __builtin_amdgcn_s_barrier();
        if (t + 2 < nk) stage(t + 2, nx2);

        bf16x8 af[4], bfr[2];
        #pragma unroll
        for (int fi = 0; fi < 4; ++fi)
            af[fi] = *(const bf16x8*)&As[cur][(wr * 64 + fi * 16 + l15) * 32 + q * 8];
        #pragma unroll
        for (int fj = 0; fj < 2; ++fj)
            bfr[fj] = *(const bf16x8*)&Bs[cur][(wc * 32 + fj * 16 + l15) * 32 + q * 8];
        #pragma unroll
        for (int fi = 0; fi < 4; ++fi)
            #pragma unroll
            for (int fj = 0; fj < 2; ++fj)
                acc[fi][fj] = __builtin_amdgcn_mfma_f32_16x16x32_bf16(
                    af[fi], bfr[fj], acc[fi][fj], 0, 0, 0);

        cur = (cur == 2) ? 0 : cur + 1;
        nx2 = (nx2 == 2) ? 0 : nx2 + 1;
    }

    #pragma unroll
    for (int fi = 0; fi < 4; ++fi) {
        #pragma unroll
        for (int reg = 0; reg < 4; ++reg) {
            int row = row0 + wr * 64 + fi * 16 + q * 4 + reg;
            #pragma unroll
            for (int fj = 0; fj < 2; ++fj) {
                int col = col0 + wc * 32 + fj * 16 + l15;
                float v = acc[fi][fj][reg] + bias[col];
                if (dogelu) v = 0.5f * v * (1.0f + erff(v * 0.70710678118654752f));
                size_t off = (size_t)row * Mo + col;
                if (R1) v += R1[off];
                if (R2) v += bf2f(R2[off]);
                if (Cb) Cb[off] = f2bf(v);
                else    Cf[off] = v;
            }
        }
    }
}

// ---------------- bf16 MFMA GEMM, 64x64 tile, BK=64 ----------------------
// Depth-2 counted-vmcnt pipeline + XOR chunk-swizzle (both-sides involution).
__global__ __launch_bounds__(256) void gemm_mfma64(
    const unsigned short* __restrict__ A, int lda,
    const unsigned short* __restrict__ Bt,
    const float* __restrict__ bias,
    const float* __restrict__ R1,
    const unsigned short* __restrict__ R2,
    float* __restrict__ Cf, unsigned short* __restrict__ Cb,
    int K, int Mo, int dogelu)
{
    __shared__ __align__(16) unsigned short As[3][64 * 64];
    __shared__ __align__(16) unsigned short Bs[3][64 * 64];
    const int tid = threadIdx.x;
    const int wave = tid >> 6, lane = tid & 63;
    const int row0 = blockIdx.y * 64, col0 = blockIdx.x * 64;
    const int l15 = lane & 15, q = lane >> 4;

    f32x4 acc[4];
    const f32x4 zz = {0.f, 0.f, 0.f, 0.f};
    #pragma unroll
    for (int j = 0; j < 4; ++j) acc[j] = zz;

    const int nk = K >> 6;
    auto stage = [&](int t, int buf) {
        const int k0 = t * 64;
        #pragma unroll
        for (int r = 0; r < 2; ++r) {
            int idx = r * 256 + tid;
            int row = idx >> 3;
            int kc  = (idx & 7) ^ (row & 7);
            gl_lds16(&A[(size_t)(row0 + row) * lda + k0 + kc * 8],
                     &As[buf][(size_t)(r * 256 + wave * 64) * 8]);
            gl_lds16(&Bt[(size_t)(col0 + row) * K + k0 + kc * 8],
                     &Bs[buf][(size_t)(r * 256 + wave * 64) * 8]);
        }
    };
    stage(0, 0);
    if (nk > 1) stage(1, 1);

    int cur = 0, nx2 = 2;
    for (int t = 0; t < nk; ++t) {
        if (t + 1 < nk) asm volatile("s_waitcnt vmcnt(4)" ::: "memory");
        else            asm volatile("s_waitcnt vmcnt(0)" ::: "memory");
        __builtin_amdgcn_s_barrier();
        if (t + 2 < nk) stage(t + 2, nx2);

        #pragma unroll
        for (int ks = 0; ks < 2; ++ks) {
            const int cx = ((ks * 4 + q) ^ (l15 & 7)) * 8;   // swizzled chunk
            bf16x8 af = *(const bf16x8*)&As[cur][(wave * 16 + l15) * 64 + cx];
            bf16x8 bfr[4];
            #pragma unroll
            for (int fj = 0; fj < 4; ++fj)
                bfr[fj] = *(const bf16x8*)&Bs[cur][(fj * 16 + l15) * 64 + cx];
            #pragma unroll
            for (int fj = 0; fj < 4; ++fj)
                acc[fj] = __builtin_amdgcn_mfma_f32_16x16x32_bf16(af, bfr[fj], acc[fj], 0, 0, 0);
        }

        cur = (cur == 2) ? 0 : cur + 1;
        nx2 = (nx2 == 2) ? 0 : nx2 + 1;
    }

    #pragma unroll
    for (int reg = 0; reg < 4; ++reg) {
        int row = row0 + wave * 16 + q * 4 + reg;
        #pragma unroll
        for (int fj = 0; fj < 4; ++fj) {
            int col = col0 + fj * 16 + l15;
            float v = acc[fj][reg] + bias[col];
            if (dogelu) v = 0.5f * v * (1.0f + erff(v * 0.70710678118654752f));
            size_t off = (size_t)row * Mo + col;
            if (R1) v += R1[off];
            if (R2) v += bf2f(R2[off]);
            if (Cb) Cb[off] = f2bf(v);
            else    Cf[off] = v;
        }
    }
}

// ---------------- MFMA flash attention, split-K, LDS-staged K/V -----------
// Round-6 proven version (60us): 4 waves, grid (32,16,2). K/V staged to LDS
// (coalesced); T14 reg-prefetch of tile t+1 before compute of t; M direct
// from global; log2-domain softmax; T13 defer-max; deferred z reductions.
__global__ __launch_bounds__(256, 4) void attn_mfma_split(
    const unsigned short* __restrict__ Q, int ldq,
    const unsigned short* __restrict__ Kp, int ldk,
    const unsigned short* __restrict__ Vt,   // [16 bh][64 d][2048 s]
    const float* __restrict__ M,
    unsigned short* __restrict__ Opart,      // [2][16][2048][64] bf16
    float* __restrict__ stats)               // [2][16][2048][4] f32 (rm in log2 units)
{
    __shared__ __align__(16) unsigned short Ks[64 * 72];
    __shared__ __align__(16) unsigned short Vs[64 * 72];
    __shared__ __align__(16) unsigned short Ps_all[4][16 * 72];  // per-wave P

    const int bh = blockIdx.y, b = bh >> 3, h = bh & 7;
    const int q0 = blockIdx.x * 64;
    const int p = blockIdx.z;
    const int tid = threadIdx.x, wave = tid >> 6, lane = tid & 63;
    const int l15 = lane & 15, quad = lane >> 4;
    const int iRow = q0 + wave * 16 + l15;
    const int kBeg = p * (S_LEN / 2), kEnd = kBeg + (S_LEN / 2);

    unsigned short* Ps = &Ps_all[wave][0];   // [16][72] shorts

    // Q fragments, pre-scaled into log2 domain
    bf16x8 qf[2];
    {
        const unsigned short* qp = Q + (size_t)(b * S_LEN + iRow) * ldq + h * HDIM + quad * 8;
        #pragma unroll
        for (int ks = 0; ks < 2; ++ks) {
            union { bf16x8 v; unsigned short u[8]; } tq;
            tq.v = *(const bf16x8*)(qp + ks * 32);
            #pragma unroll
            for (int e = 0; e < 8; ++e)
                tq.u[e] = f2bf(bf2f(tq.u[e]) * (0.125f * LOG2E));
            qf[ks] = tq.v;
        }
    }

    // coalesced staging addresses
    const int srow = tid >> 3;            // 0..31
    const int scol = (tid & 7) * 8;       // 0..56 shorts
    const unsigned short* kg = Kp + ((size_t)b * S_LEN) * ldk + h * HDIM + scol;
    const unsigned short* vg = Vt + ((size_t)bh * 64 + srow) * S_LEN + scol;
    const float* mrow = M + ((size_t)b * S_LEN + iRow) * S_LEN + quad * 4;

    float rm = -INFINITY, rZ = 0.f, rZm = 0.f;   // rZ/rZm: per-lane partials
    f32x4 oacc[4];
    const f32x4 zz = {0.f, 0.f, 0.f, 0.f};
    #pragma unroll
    for (int dt = 0; dt < 4; ++dt) oacc[dt] = zz;

    // prologue: stage first tile
    int4 kv0 = *(const int4*)(kg + (size_t)(kBeg + srow) * ldk);
    int4 kv1 = *(const int4*)(kg + (size_t)(kBeg + srow + 32) * ldk);
    int4 vv0 = *(const int4*)(vg + kBeg);
    int4 vv1 = *(const int4*)(vg + 32 * S_LEN + kBeg);
    *(int4*)&Ks[srow * 72 + scol]        = kv0;
    *(int4*)&Ks[(srow + 32) * 72 + scol] = kv1;
    *(int4*)&Vs[srow * 72 + scol]        = vv0;
    *(int4*)&Vs[(srow + 32) * 72 + scol] = vv1;
    __syncthreads();

    for (int k0 = kBeg; k0 < kEnd; k0 += 64) {
        const bool more = (k0 + 64 < kEnd);
        // T14: issue next tile's global loads now; latency hides under compute
        if (more) {
            kv0 = *(const int4*)(kg + (size_t)(k0 + 64 + srow) * ldk);
            kv1 = *(const int4*)(kg + (size_t)(k0 + 64 + srow + 32) * ldk);
            vv0 = *(const int4*)(vg + k0 + 64);
            vv1 = *(const int4*)(vg + 32 * S_LEN + k0 + 64);
        }
        float4 m4[4];
        #pragma unroll
        for (int jt = 0; jt < 4; ++jt)
            m4[jt] = *(const float4*)(mrow + k0 + jt * 16);

        // QK^T from LDS K
        f32x4 sacc[4];
        #pragma unroll
        for (int jt = 0; jt < 4; ++jt) sacc[jt] = zz;
        __builtin_amdgcn_s_setprio(1);
        #pragma unroll
        for (int jt = 0; jt < 4; ++jt) {
            bf16x8 kf0 = *(const bf16x8*)&Ks[(jt * 16 + l15) * 72 + quad * 8];
            bf16x8 kf1 = *(const bf16x8*)&Ks[(jt * 16 + l15) * 72 + 32 + quad * 8];
            sacc[jt] = __builtin_amdgcn_mfma_f32_16x16x32_bf16(kf0, qf[0], sacc[jt], 0, 0, 0);
            sacc[jt] = __builtin_amdgcn_mfma_f32_16x16x32_bf16(kf1, qf[1], sacc[jt], 0, 0, 0);
        }
        __builtin_amdgcn_s_setprio(0);

        // masked scores + tree row-max (log2 domain)
        float mxj[4];
        #pragma unroll
        for (int jt = 0; jt < 4; ++jt) {
            float mm[4] = {m4[jt].x, m4[jt].y, m4[jt].z, m4[jt].w};
            #pragma unroll
            for (int r = 0; r < 4; ++r)
                sacc[jt][r] = sacc[jt][r] * mm[r];
            mxj[jt] = fmaxf(fmaxf(sacc[jt][0], sacc[jt][1]),
                            fmaxf(sacc[jt][2], sacc[jt][3]));
        }
        float mx = fmaxf(fmaxf(mxj[0], mxj[1]), fmaxf(mxj[2], mxj[3]));
        mx = fmaxf(mx, __shfl_xor(mx, 16));
        mx = fmaxf(mx, __shfl_xor(mx, 32));
        // T13 defer-max: only rescale when the running max actually grows >8
        if (!__all(mx <= rm + 8.0f)) {
            float mn = fmaxf(rm, mx);
            float al = __builtin_amdgcn_exp2f(rm - mn);
            rm = mn; rZ *= al; rZm *= al;
            #pragma unroll
            for (int dt = 0; dt < 4; ++dt)
                #pragma unroll
                for (int r = 0; r < 4; ++r) oacc[dt][r] *= al;
        }

        // P = exp2(s - rm); per-lane z/zm accumulation (no shfl here)
        float z = 0.f, zm = 0.f;
        #pragma unroll
        for (int jt = 0; jt < 4; ++jt) {
            float mm[4] = {m4[jt].x, m4[jt].y, m4[jt].z, m4[jt].w};
            float pv[4];
            #pragma unroll
            for (int r = 0; r < 4; ++r) {
                float e = __builtin_amdgcn_exp2f(sacc[jt][r] - rm);
                float pm = e * mm[r];
                z += e; zm += pm; pv[r] = pm;
            }
            unsigned lo, hi;
            asm("v_cvt_pk_bf16_f32 %0, %1, %2" : "=v"(lo) : "v"(pv[0]), "v"(pv[1]));
            asm("v_cvt_pk_bf16_f32 %0, %1, %2" : "=v"(hi) : "v"(pv[2]), "v"(pv[3]));
            uint2 pk; pk.x = lo; pk.y = hi;
            *(uint2*)&Ps[l15 * 72 + jt * 16 + quad * 4] = pk;
        }
        rZ += z; rZm += zm;

        // PV from LDS V; P from per-wave LDS (no cross-wave sync needed)
        bf16x8 pf0 = *(const bf16x8*)&Ps[l15 * 72 + quad * 8];
        bf16x8 pf1 = *(const bf16x8*)&Ps[l15 * 72 + 32 + quad * 8];
        __builtin_amdgcn_s_setprio(1);
        #pragma unroll
        for (int dt = 0; dt < 4; ++dt) {
            bf16x8 vf0 = *(const bf16x8*)&Vs[(dt * 16 + l15) * 72 + quad * 8];
            bf16x8 vf1 = *(const bf16x8*)&Vs[(dt * 16 + l15) * 72 + 32 + quad * 8];
            oacc[dt] = __builtin_amdgcn_mfma_f32_16x16x32_bf16(vf0, pf0, oacc[dt], 0, 0, 0);
            oacc[dt] = __builtin_amdgcn_mfma_f32_16x16x32_bf16(vf1, pf1, oacc[dt], 0, 0, 0);
        }
        __builtin_amdgcn_s_setprio(0);

        // commit prefetched tile to LDS
        if (more) {
            __syncthreads();
            *(int4*)&Ks[srow * 72 + scol]        = kv0;
            *(int4*)&Ks[(srow + 32) * 72 + scol] = kv1;
            *(int4*)&Vs[srow * 72 + scol]        = vv0;
            *(int4*)&Vs[(srow + 32) * 72 + scol] = vv1;
            __syncthreads();
        }
    }

    // deferred z/zm cross-lane reduction (once instead of per-tile)
    rZ  += __shfl_xor(rZ, 16);  rZ  += __shfl_xor(rZ, 32);
    rZm += __shfl_xor(rZm, 16); rZm += __shfl_xor(rZm, 32);

    unsigned short* op = Opart + (((size_t)(p * 16 + bh) * S_LEN + iRow) * 64);
    #pragma unroll
    for (int dt = 0; dt < 4; ++dt) {
        unsigned lo, hi;
        asm("v_cvt_pk_bf16_f32 %0, %1, %2" : "=v"(lo) : "v"(oacc[dt][0]), "v"(oacc[dt][1]));
        asm("v_cvt_pk_bf16_f32 %0, %1, %2" : "=v"(hi) : "v"(oacc[dt][2]), "v"(oacc[dt][3]));
        uint2 o2; o2.x = lo; o2.y = hi;
        *(uint2*)(op + dt * 16 + quad * 4) = o2;
    }
    if (quad == 0) {
        float4 st; st.x = rm; st.y = rZ; st.z = rZm; st.w = 0.f;
        *(float4*)&stats[(((size_t)p * 16 + bh) * S_LEN + iRow) * 4] = st;
    }
}

// ---------------- combine the two split-K partials ----------------
// NOTE: stats.x (running max) is in log2 units -> exp2 here.
__global__ __launch_bounds__(256) void attn_combine(
    const unsigned short* __restrict__ Opart, const float* __restrict__ stats,
    unsigned short* __restrict__ O)
{
    const int bh = blockIdx.y, b = bh >> 3, h = bh & 7;
    const int q0 = blockIdx.x * 64;
    const int tid = threadIdx.x;
    const int i = tid >> 2, dq = (tid & 3) * 16;
    const int qg = q0 + i;

    float4 s0 = *(const float4*)&stats[(((size_t)0 * 16 + bh) * S_LEN + qg) * 4];
    float4 s1 = *(const float4*)&stats[(((size_t)1 * 16 + bh) * S_LEN + qg) * 4];
    float ms = fmaxf(s0.x, s1.x);
    float w0 = __builtin_amdgcn_exp2f(s0.x - ms), w1 = __builtin_amdgcn_exp2f(s1.x - ms);
    float Z  = w0 * s0.y + w1 * s1.y;
    float Zm = w0 * s0.z + w1 * s1.z;
    float inv = 1.0f / (Zm + 1e-8f * Z);
    w0 *= inv; w1 *= inv;

    const unsigned short* p0 = Opart + (((size_t)0 * 16 + bh) * S_LEN + qg) * 64 + dq;
    const unsigned short* p1 = Opart + (((size_t)1 * 16 + bh) * S_LEN + qg) * 64 + dq;
    union { int4 v; unsigned short u[8]; } a0, a1, r;
    unsigned short* dst = O + (size_t)(b * S_LEN + qg) * DMODEL + h * HDIM + dq;
    #pragma unroll
    for (int half = 0; half < 2; ++half) {
        a0.v = *(const int4*)(p0 + half * 8);
        a1.v = *(const int4*)(p1 + half * 8);
        #pragma unroll
        for (int e = 0; e < 8; ++e)
            r.u[e] = f2bf(w0 * bf2f(a0.u[e]) + w1 * bf2f(a1.u[e]));
        *(int4*)(dst + half * 8) = r.v;
    }
}

// ---------------- launch ----------------
extern "C" void kernel_launch(void* const* d_in, const int* in_sizes, int n_in,
                              void* d_out, int out_size, void* d_ws, size_t ws_size,
                              hipStream_t stream)
{
    const float* gene_emb = (const float*)d_in[0];
    const float* expr_emb = (const float*)d_in[1];
    const float* M        = (const float*)d_in[2];
    const float* g_wq = (const float*)d_in[3];
    const float* g_wk = (const float*)d_in[4];
    const float* g_wv = (const float*)d_in[5];
    const float* g_wo = (const float*)d_in[6];
    const float* g_bq = (const float*)d_in[7];
    const float* g_bk = (const float*)d_in[8];
    const float* g_bv = (const float*)d_in[9];
    const float* g_bo = (const float*)d_in[10];
    const float* e_wf = (const float*)d_in[11];
    const float* e_bf = (const float*)d_in[12];
    const float* e_wq = (const float*)d_in[13];
    const float* e_wk = (const float*)d_in[14];
    const float* e_wv = (const float*)d_in[15];
    const float* e_wo = (const float*)d_in[16];
    const float* e_bq = (const float*)d_in[17];
    const float* e_bk = (const float*)d_in[18];
    const float* e_bv = (const float*)d_in[19];
    const float* e_bo = (const float*)d_in[20];
    const float* ln_g1_w = (const float*)d_in[21];
    const float* ln_g2_w = (const float*)d_in[22];
    const float* ln_e1_w = (const float*)d_in[23];
    const float* ln_e2_w = (const float*)d_in[24];
    const float* ln_g1_b = (const float*)d_in[25];
    const float* ln_g2_b = (const float*)d_in[26];
    const float* ln_e1_b = (const float*)d_in[27];
    const float* ln_e2_b = (const float*)d_in[28];
    const float* fg_w1 = (const float*)d_in[29];
    const float* fg_b1 = (const float*)d_in[30];
    const float* fg_w2 = (const float*)d_in[31];
    const float* fg_b2 = (const float*)d_in[32];
    const float* fe_w1 = (const float*)d_in[33];
    const float* fe_b1 = (const float*)d_in[34];
    const float* fe_w2 = (const float*)d_in[35];
    const float* fe_b2 = (const float*)d_in[36];

    float* out_gene = (float*)d_out;
    float* out_expr = out_gene + (size_t)NROWS * DMODEL;

    // ---- workspace (MB offsets), round-6 proven aliasing ----
    char* ws = (char*)d_ws;
    const size_t MB1 = 1024 * 1024;
    unsigned short* bufA16  = (unsigned short*)(ws + 0 * MB1);   // 0-4
    unsigned short* bufAt16 = (unsigned short*)(ws + 4 * MB1);   // 4-8 attn combined
    unsigned short* bufQKV  = (unsigned short*)(ws + 8 * MB1);   // 8-20 gene [4096][1536]
    unsigned short* bufQKe  = (unsigned short*)(ws + 8 * MB1);   // 8-16 expr [4096][1024]
    unsigned short* bufV16  = (unsigned short*)(ws + 16 * MB1);  // 16-20 expr V
    unsigned short* bufVt   = (unsigned short*)(ws + 20 * MB1);  // 20-24
    unsigned short* bufCat  = (unsigned short*)(ws + 24 * MB1);  // 24-32 expr concat (dead pre-attn)
    unsigned short* bufOp   = (unsigned short*)(ws + 24 * MB1);  // 24-32 attn O partials
    float*          bufSt   = (float*)(ws + 32 * MB1);           // 32-33 attn stats
    float*          bufX    = (float*)(ws + 33 * MB1);           // 33-41 fp32 residual
    unsigned short* bufH16  = (unsigned short*)(ws + 8 * MB1);   // 8-24 FFN hidden
    char* wp = ws + 41 * MB1;
    unsigned short* sq8    = (unsigned short*)wp;                 // 8 x 512x512
    unsigned short* gwq_t  = sq8 + 0 * 512 * 512;
    unsigned short* gwo_t  = sq8 + 3 * 512 * 512;
    unsigned short* ewq_t  = sq8 + 4 * 512 * 512;
    unsigned short* ewv_t  = sq8 + 6 * 512 * 512;
    unsigned short* ewo_t  = sq8 + 7 * 512 * 512;
    unsigned short* ewf_t  = sq8 + 8 * 512 * 512;                 // 1024x512
    unsigned short* ffn1   = ewf_t + 1024 * 512;                  // 2 x [2048][512]
    unsigned short* fgw1_t = ffn1;
    unsigned short* few1_t = ffn1 + 512 * 2048;
    unsigned short* ffn2   = few1_t + 512 * 2048;                 // 2 x [512][2048]
    unsigned short* fgw2_t = ffn2;
    unsigned short* few2_t = ffn2 + 2048 * 512;
    float* biasg = (float*)(few2_t + 2048 * 512);
    float* biase = biasg + 1536;

    dim3 blk(256);
    dim3 blk512(512);
    dim3 ln_grid(NROWS);
    dim3 g512s(8, 64);    // 64x64 tiles, Mo=512 -> 512 blocks (2 blocks/CU)
    dim3 g1024(8, 32);
    dim3 g1536(12, 32);
    dim3 g2048(16, 32);
    dim3 attn_grid(S_LEN / 64, 16, 2);
    dim3 comb_grid(S_LEN / 64, 16);
    dim3 vt_grid(S_LEN / 64, NHEAD, 2);

    // ---- ALL weight prep: one launch ----
    prep_all<<<dim3(6666), blk, 0, stream>>>(
        g_wq, g_wk, g_wv, g_wo, e_wq, e_wk, e_wv, e_wo,
        e_wf, fg_w1, fe_w1, fg_w2, fe_w2,
        g_bq, g_bk, g_bv, e_bq, e_bk,
        sq8, biasg, biase);

    // ---------------- gene branch ----------------
    ln_kernel<<<ln_grid, blk, 0, stream>>>(gene_emb, ln_g1_w, ln_g1_b, bufA16, 512);
    gemm_mfma<<<g1536, blk512, 0, stream>>>(bufA16, 512, gwq_t, biasg, nullptr, nullptr, nullptr, bufQKV, 512, 1536, 0);
    vtrans<<<vt_grid, blk, 0, stream>>>(bufQKV + 1024, 1536, bufVt);
    attn_mfma_split<<<attn_grid, blk, 0, stream>>>(bufQKV, 1536, bufQKV + 512, 1536, bufVt, M, bufOp, bufSt);
    attn_combine<<<comb_grid, blk, 0, stream>>>(bufOp, bufSt, bufAt16);
    gemm_mfma64<<<g512s, blk, 0, stream>>>(bufAt16, 512, gwo_t, g_bo, gene_emb, nullptr, bufX, nullptr, 512, 512, 0);
    ln_kernel<<<ln_grid, blk, 0, stream>>>(bufX, ln_g2_w, ln_g2_b, bufA16, 512);
    gemm_mfma<<<g2048, blk512, 0, stream>>>(bufA16, 512, fgw1_t, fg_b1, nullptr, nullptr, nullptr, bufH16, 512, 2048, 1);
    gemm_mfma64<<<g512s, blk, 0, stream>>>(bufH16, 2048, fgw2_t, fg_b2, bufX, bufA16, out_gene, nullptr, 2048, 512, 0);

    // ---------------- expr branch ----------------
    ln_cat_kernel<<<ln_grid, blk, 0, stream>>>(gene_emb, expr_emb, ln_e1_w, ln_e1_b, bufCat);
    gemm_mfma64<<<g512s, blk, 0, stream>>>(bufCat, 1024, ewf_t, e_bf, nullptr, nullptr, nullptr, bufA16, 1024, 512, 0);
    gemm_mfma<<<g1024, blk512, 0, stream>>>(bufA16, 512, ewq_t, biase, nullptr, nullptr, nullptr, bufQKe, 512, 1024, 0);
    gemm_mfma64<<<g512s, blk, 0, stream>>>(bufCat + 512, 1024, ewv_t, e_bv, nullptr, nullptr, nullptr, bufV16, 512, 512, 0);
    vtrans<<<vt_grid, blk, 0, stream>>>(bufV16, 512, bufVt);
    attn_mfma_split<<<attn_grid, blk, 0, stream>>>(bufQKe, 1024, bufQKe + 512, 1024, bufVt, M, bufOp, bufSt);
    attn_combine<<<comb_grid, blk, 0, stream>>>(bufOp, bufSt, bufAt16);
    gemm_mfma64<<<g512s, blk, 0, stream>>>(bufAt16, 512, ewo_t, e_bo, expr_emb, nullptr, bufX, nullptr, 512, 512, 0);
    ln_kernel<<<ln_grid, blk, 0, stream>>>(bufX, ln_e2_w, ln_e2_b, bufA16, 512);
    gemm_mfma<<<g2048, blk512, 0, stream>>>(bufA16, 512, few1_t, fe_b1, nullptr, nullptr, nullptr, bufH16, 512, 2048, 1);
    gemm_mfma64<<<g512s, blk, 0, stream>>>(bufH16, 2048, few2_t, fe_b2, bufX, bufA16, out_expr, nullptr, 2048, 512, 0);
}

// Round 10
// 477.622 us; speedup vs baseline: 1.1510x; 1.0413x over previous
//
#include <hip/hip_runtime.h>
#include <math.h>

// Problem constants
#define S_LEN 2048
#define DMODEL 512
#define NROWS 4096   // B*S
#define NHEAD 8
#define HDIM 64
#define LOG2E 1.4426950408889634f

typedef __attribute__((ext_vector_type(8))) __bf16 bf16x8;
typedef __attribute__((ext_vector_type(4))) float f32x4;

__device__ inline float bf2f(unsigned short h) {
    unsigned u = ((unsigned)h) << 16;
    return __builtin_bit_cast(float, u);
}
__device__ inline unsigned short f2bf(float f) {
    unsigned u = __builtin_bit_cast(unsigned, f);
    return (unsigned short)((u + 0x7fffu + ((u >> 16) & 1u)) >> 16);
}

// async global->LDS, 16B per lane; LDS dest = wave-uniform base + lane*16
__device__ inline void gl_lds16(const unsigned short* g, unsigned short* l) {
    __builtin_amdgcn_global_load_lds(
        (const __attribute__((address_space(1))) void*)g,
        (__attribute__((address_space(3))) void*)l, 16, 0, 0);
}

// ---------------- ALL weight prep in ONE launch --------------------------
__global__ __launch_bounds__(256) void prep_all(
    const float* g_wq, const float* g_wk, const float* g_wv, const float* g_wo,
    const float* e_wq, const float* e_wk, const float* e_wv, const float* e_wo,
    const float* e_wf, const float* fg_w1, const float* fe_w1,
    const float* fg_w2, const float* fe_w2,
    const float* g_bq, const float* g_bk, const float* g_bv,
    const float* e_bq, const float* e_bk,
    unsigned short* __restrict__ wbase, float* __restrict__ biasg,
    float* __restrict__ biase)
{
    const int id = blockIdx.x;
    const int tid = threadIdx.x;
    if (id >= 6656) {
        int t = id - 6656;
        if (t < 6) {
            int i = t * 256 + tid;
            biasg[i] = (i < 512) ? g_bq[i] : (i < 1024) ? g_bk[i - 512] : g_bv[i - 1024];
        } else {
            int i = (t - 6) * 256 + tid;
            biase[i] = (i < 512) ? e_bq[i] : e_bk[i - 512];
        }
        return;
    }
    const float* W; unsigned short* Wt; int K, Mo, bx, by;
    if (id < 2048) {
        const float* srcs[8] = {g_wq, g_wk, g_wv, g_wo, e_wq, e_wk, e_wv, e_wo};
        int m = id >> 8, t = id & 255;
        W = srcs[m]; Wt = wbase + (size_t)m * 512 * 512; K = 512; Mo = 512;
        bx = (t & 15) * 32; by = (t >> 4) * 32;
    } else if (id < 2560) {
        int t = id - 2048;
        W = e_wf; Wt = wbase + 8 * 512 * 512; K = 1024; Mo = 512;
        bx = (t & 15) * 32; by = (t >> 4) * 32;
    } else if (id < 4608) {
        int t = id - 2560; int which = t >> 10; t &= 1023;
        W = which ? fe_w1 : fg_w1;
        Wt = wbase + 8 * 512 * 512 + 1024 * 512 + (size_t)which * 512 * 2048;
        K = 512; Mo = 2048;
        bx = (t & 63) * 32; by = (t >> 6) * 32;
    } else {
        int t = id - 4608; int which = t >> 10; t &= 1023;
        W = which ? fe_w2 : fg_w2;
        Wt = wbase + 8 * 512 * 512 + 1024 * 512 + 2 * 512 * 2048 + (size_t)which * 2048 * 512;
        K = 2048; Mo = 512;
        bx = (t & 15) * 32; by = (t >> 4) * 32;
    }
    __shared__ float tsh[32][33];
    const int tx = tid & 31, ty = tid >> 5;
    #pragma unroll
    for (int r = 0; r < 4; ++r)
        tsh[ty + 8 * r][tx] = W[(size_t)(by + ty + 8 * r) * Mo + bx + tx];
    __syncthreads();
    #pragma unroll
    for (int r = 0; r < 4; ++r)
        Wt[(size_t)(bx + ty + 8 * r) * K + by + tx] = f2bf(tsh[tx][ty + 8 * r]);
}

// ---------------- LayerNorm: fp32 in, bf16 out (strided) ----------------
__global__ __launch_bounds__(256) void ln_kernel(
    const float* __restrict__ x, const float* __restrict__ w,
    const float* __restrict__ b, unsigned short* __restrict__ y, int ostride)
{
    __shared__ float red[8];
    const int row = blockIdx.x;
    const float* xr = x + (size_t)row * DMODEL;
    const int t = threadIdx.x;
    float v0 = xr[t];
    float v1 = xr[t + 256];
    float s  = v0 + v1;
    float sq = v0 * v0 + v1 * v1;
    #pragma unroll
    for (int o = 32; o > 0; o >>= 1) {
        s  += __shfl_down(s, o);
        sq += __shfl_down(sq, o);
    }
    int wid = t >> 6, lane = t & 63;
    if (lane == 0) { red[wid] = s; red[4 + wid] = sq; }
    __syncthreads();
    float mean = (red[0] + red[1] + red[2] + red[3]) * (1.0f / 512.0f);
    float msq  = (red[4] + red[5] + red[6] + red[7]) * (1.0f / 512.0f);
    float var  = msq - mean * mean;
    float rs   = rsqrtf(var + 1e-5f);
    y[(size_t)row * ostride + t]       = f2bf((v0 - mean) * rs * w[t] + b[t]);
    y[(size_t)row * ostride + t + 256] = f2bf((v1 - mean) * rs * w[t + 256] + b[t + 256]);
}

// ---------------- fused: cast(gene)->left half, LN(expr)->right half ------
__global__ __launch_bounds__(256) void ln_cat_kernel(
    const float* __restrict__ xg, const float* __restrict__ xe,
    const float* __restrict__ w, const float* __restrict__ b,
    unsigned short* __restrict__ y)   // [4096][1024]
{
    __shared__ float red[8];
    const int row = blockIdx.x;
    const int t = threadIdx.x;
    const float* gr = xg + (size_t)row * DMODEL;
    const float* er = xe + (size_t)row * DMODEL;
    float g0 = gr[t], g1 = gr[t + 256];
    float v0 = er[t], v1 = er[t + 256];
    float s  = v0 + v1;
    float sq = v0 * v0 + v1 * v1;
    #pragma unroll
    for (int o = 32; o > 0; o >>= 1) {
        s  += __shfl_down(s, o);
        sq += __shfl_down(sq, o);
    }
    int wid = t >> 6, lane = t & 63;
    if (lane == 0) { red[wid] = s; red[4 + wid] = sq; }
    __syncthreads();
    float mean = (red[0] + red[1] + red[2] + red[3]) * (1.0f / 512.0f);
    float msq  = (red[4] + red[5] + red[6] + red[7]) * (1.0f / 512.0f);
    float var  = msq - mean * mean;
    float rs   = rsqrtf(var + 1e-5f);
    unsigned short* yr = y + (size_t)row * 1024;
    yr[t]             = f2bf(g0);
    yr[t + 256]       = f2bf(g1);
    yr[512 + t]       = f2bf((v0 - mean) * rs * w[t] + b[t]);
    yr[512 + t + 256] = f2bf((v1 - mean) * rs * w[t + 256] + b[t + 256]);
}

// ---------------- V transpose: Vt[(b*8+h)*64 + d][s] = V[b*2048+s][h*64+d] --
__global__ __launch_bounds__(256) void vtrans(
    const unsigned short* __restrict__ V, int ldv, unsigned short* __restrict__ Vt)
{
    __shared__ unsigned short t[64][72];
    const int s0 = blockIdx.x * 64, h = blockIdx.y, b = blockIdx.z;
    const int tid = threadIdx.x;
    {
        const int r = tid >> 2, c = (tid & 3) * 16;
        const unsigned short* src = V + (size_t)(b * S_LEN + s0 + r) * ldv + h * 64 + c;
        *(int4*)&t[r][c]     = *(const int4*)(src);
        *(int4*)&t[r][c + 8] = *(const int4*)(src + 8);
    }
    __syncthreads();
    {
        const int d = tid >> 2, s = (tid & 3) * 16;
        unsigned short* dst = Vt + ((size_t)((b * 8 + h) * 64 + d)) * S_LEN + s0 + s;
        unsigned short tmp[16];
        #pragma unroll
        for (int e = 0; e < 16; ++e) tmp[e] = t[s + e][d];
        *(int4*)dst       = *(int4*)&tmp[0];
        *(int4*)(dst + 8) = *(int4*)&tmp[8];
    }
}

// ---------------- bf16 MFMA GEMM, 128x128 tile, BK=32, 8 WAVES -----------
// 512 threads; waves as 2x4 over 64x32 sub-tiles. Validated (+~24us r9).
__global__ __launch_bounds__(512) void gemm_mfma(
    const unsigned short* __restrict__ A, int lda,
    const unsigned short* __restrict__ Bt,
    const float* __restrict__ bias,
    const float* __restrict__ R1,
    const unsigned short* __restrict__ R2,
    float* __restrict__ Cf, unsigned short* __restrict__ Cb,
    int K, int Mo, int dogelu)
{
    __shared__ __align__(16) unsigned short As[3][128 * 32];
    __shared__ __align__(16) unsigned short Bs[3][128 * 32];
    const int tid = threadIdx.x;
    const int wave = tid >> 6, lane = tid & 63;
    const int wr = wave >> 2, wc = wave & 3;       // 2x4 wave grid
    const int row0 = blockIdx.y * 128, col0 = blockIdx.x * 128;
    const int l15 = lane & 15, q = lane >> 4;

    f32x4 acc[4][2];
    const f32x4 zz = {0.f, 0.f, 0.f, 0.f};
    #pragma unroll
    for (int i = 0; i < 4; ++i)
        #pragma unroll
        for (int j = 0; j < 2; ++j) acc[i][j] = zz;

    const int nk = K >> 5;
    auto stage = [&](int t, int buf) {
        const int k0 = t * 32;
        const int row = tid >> 2, kc = tid & 3;    // 512 threads cover 128x4
        gl_lds16(&A[(size_t)(row0 + row) * lda + k0 + kc * 8],
                 &As[buf][(size_t)(wave * 64) * 8]);
        gl_lds16(&Bt[(size_t)(col0 + row) * K + k0 + kc * 8],
                 &Bs[buf][(size_t)(wave * 64) * 8]);
    };
    stage(0, 0);
    if (nk > 1) stage(1, 1);

    int cur = 0, nx2 = 2;
    for (int t = 0; t < nk; ++t) {
        if (t + 1 < nk) asm volatile("s_waitcnt vmcnt(2)" ::: "memory");
        else            asm volatile("s_waitcnt vmcnt(0)" ::: "memory");
        __builtin_amdgcn_s_barrier();
        if (t + 2 < nk) stage(t + 2, nx2);

        bf16x8 af[4], bfr[2];
        #pragma unroll
        for (int fi = 0; fi < 4; ++fi)
            af[fi] = *(const bf16x8*)&As[cur][(wr * 64 + fi * 16 + l15) * 32 + q * 8];
        #pragma unroll
        for (int fj = 0; fj < 2; ++fj)
            bfr[fj] = *(const bf16x8*)&Bs[cur][(wc * 32 + fj * 16 + l15) * 32 + q * 8];
        #pragma unroll
        for (int fi = 0; fi < 4; ++fi)
            #pragma unroll
            for (int fj = 0; fj < 2; ++fj)
                acc[fi][fj] = __builtin_amdgcn_mfma_f32_16x16x32_bf16(
                    af[fi], bfr[fj], acc[fi][fj], 0, 0, 0);

        cur = (cur == 2) ? 0 : cur + 1;
        nx2 = (nx2 == 2) ? 0 : nx2 + 1;
    }

    #pragma unroll
    for (int fi = 0; fi < 4; ++fi) {
        #pragma unroll
        for (int reg = 0; reg < 4; ++reg) {
            int row = row0 + wr * 64 + fi * 16 + q * 4 + reg;
            #pragma unroll
            for (int fj = 0; fj < 2; ++fj) {
                int col = col0 + wc * 32 + fj * 16 + l15;
                float v = acc[fi][fj][reg] + bias[col];
                if (dogelu) v = 0.5f * v * (1.0f + erff(v * 0.70710678118654752f));
                size_t off = (size_t)row * Mo + col;
                if (R1) v += R1[off];
                if (R2) v += bf2f(R2[off]);
                if (Cb) Cb[off] = f2bf(v);
                else    Cf[off] = v;
            }
        }
    }
}

// ---------------- bf16 MFMA GEMM, 64x64 tile, BK=64, 8 WAVES -------------
// Round-10 change: 512 threads on the SAME 64x64 tile. Waves as 4x2
// (per-wave 16x32 sub-tile, acc[2] -> tiny reg state, no spill risk).
// LDS unchanged (48 KB triple-buffer) -> still 2 blocks/CU, so waves/CU
// doubles 8 -> 16 (the validated occupancy lever, rounds 8/9).
// Staging: 1 chunk/thread/matrix (512 threads cover 64 rows x 8 chunks);
// same XOR involution swizzle (read math identical: row&7 == l15&7).
// Counted vmcnt(2): 2 loads/thread/stage, 2 tiles in flight.
__global__ __launch_bounds__(512) void gemm_mfma64(
    const unsigned short* __restrict__ A, int lda,
    const unsigned short* __restrict__ Bt,
    const float* __restrict__ bias,
    const float* __restrict__ R1,
    const unsigned short* __restrict__ R2,
    float* __restrict__ Cf, unsigned short* __restrict__ Cb,
    int K, int Mo, int dogelu)
{
    __shared__ __align__(16) unsigned short As[3][64 * 64];
    __shared__ __align__(16) unsigned short Bs[3][64 * 64];
    const int tid = threadIdx.x;
    const int wave = tid >> 6, lane = tid & 63;
    const int wr = wave & 3, wc = wave >> 2;       // 4x2 wave grid
    const int row0 = blockIdx.y * 64, col0 = blockIdx.x * 64;
    const int l15 = lane & 15, q = lane >> 4;

    f32x4 acc[2];
    const f32x4 zz = {0.f, 0.f, 0.f, 0.f};
    #pragma unroll
    for (int j = 0; j < 2; ++j) acc[j] = zz;

    const int nk = K >> 6;
    auto stage = [&](int t, int buf) {
        const int k0 = t * 64;
        const int row = tid >> 3;                  // 0..63
        const int kc  = (tid & 7) ^ (row & 7);     // swizzled source chunk
        gl_lds16(&A[(size_t)(row0 + row) * lda + k0 + kc * 8],
                 &As[buf][(size_t)(wave * 64) * 8]);
        gl_lds16(&Bt[(size_t)(col0 + row) * K + k0 + kc * 8],
                 &Bs[buf][(size_t)(wave * 64) * 8]);
    };
    stage(0, 0);
    if (nk > 1) stage(1, 1);

    int cur = 0, nx2 = 2;
    for (int t = 0; t < nk; ++t) {
        if (t + 1 < nk) asm volatile("s_waitcnt vmcnt(2)" ::: "memory");
        else            asm volatile("s_waitcnt vmcnt(0)" ::: "memory");
        __builtin_amdgcn_s_barrier();
        if (t + 2 < nk) stage(t + 2, nx2);

        #pragma unroll
        for (int ks = 0; ks < 2; ++ks) {
            const int cx = ((ks * 4 + q) ^ (l15 & 7)) * 8;   // swizzled chunk
            bf16x8 af = *(const bf16x8*)&As[cur][(wr * 16 + l15) * 64 + cx];
            bf16x8 bfr[2];
            #pragma unroll
            for (int fj = 0; fj < 2; ++fj)
                bfr[fj] = *(const bf16x8*)&Bs[cur][(wc * 32 + fj * 16 + l15) * 64 + cx];
            #pragma unroll
            for (int fj = 0; fj < 2; ++fj)
                acc[fj] = __builtin_amdgcn_mfma_f32_16x16x32_bf16(af, bfr[fj], acc[fj], 0, 0, 0);
        }

        cur = (cur == 2) ? 0 : cur + 1;
        nx2 = (nx2 == 2) ? 0 : nx2 + 1;
    }

    #pragma unroll
    for (int reg = 0; reg < 4; ++reg) {
        int row = row0 + wr * 16 + q * 4 + reg;
        #pragma unroll
        for (int fj = 0; fj < 2; ++fj) {
            int col = col0 + wc * 32 + fj * 16 + l15;
            float v = acc[fj][reg] + bias[col];
            if (dogelu) v = 0.5f * v * (1.0f + erff(v * 0.70710678118654752f));
            size_t off = (size_t)row * Mo + col;
            if (R1) v += R1[off];
            if (R2) v += bf2f(R2[off]);
            if (Cb) Cb[off] = f2bf(v);
            else    Cf[off] = v;
        }
    }
}

// ---------------- MFMA flash attention, split-K, LDS-staged K/V -----------
// Round-6 proven version (60us): 4 waves, grid (32,16,2).
__global__ __launch_bounds__(256, 4) void attn_mfma_split(
    const unsigned short* __restrict__ Q, int ldq,
    const unsigned short* __restrict__ Kp, int ldk,
    const unsigned short* __restrict__ Vt,   // [16 bh][64 d][2048 s]
    const float* __restrict__ M,
    unsigned short* __restrict__ Opart,      // [2][16][2048][64] bf16
    float* __restrict__ stats)               // [2][16][2048][4] f32 (rm in log2 units)
{
    __shared__ __align__(16) unsigned short Ks[64 * 72];
    __shared__ __align__(16) unsigned short Vs[64 * 72];
    __shared__ __align__(16) unsigned short Ps_all[4][16 * 72];  // per-wave P

    const int bh = blockIdx.y, b = bh >> 3, h = bh & 7;
    const int q0 = blockIdx.x * 64;
    const int p = blockIdx.z;
    const int tid = threadIdx.x, wave = tid >> 6, lane = tid & 63;
    const int l15 = lane & 15, quad = lane >> 4;
    const int iRow = q0 + wave * 16 + l15;
    const int kBeg = p * (S_LEN / 2), kEnd = kBeg + (S_LEN / 2);

    unsigned short* Ps = &Ps_all[wave][0];   // [16][72] shorts

    // Q fragments, pre-scaled into log2 domain
    bf16x8 qf[2];
    {
        const unsigned short* qp = Q + (size_t)(b * S_LEN + iRow) * ldq + h * HDIM + quad * 8;
        #pragma unroll
        for (int ks = 0; ks < 2; ++ks) {
            union { bf16x8 v; unsigned short u[8]; } tq;
            tq.v = *(const bf16x8*)(qp + ks * 32);
            #pragma unroll
            for (int e = 0; e < 8; ++e)
                tq.u[e] = f2bf(bf2f(tq.u[e]) * (0.125f * LOG2E));
            qf[ks] = tq.v;
        }
    }

    // coalesced staging addresses
    const int srow = tid >> 3;            // 0..31
    const int scol = (tid & 7) * 8;       // 0..56 shorts
    const unsigned short* kg = Kp + ((size_t)b * S_LEN) * ldk + h * HDIM + scol;
    const unsigned short* vg = Vt + ((size_t)bh * 64 + srow) * S_LEN + scol;
    const float* mrow = M + ((size_t)b * S_LEN + iRow) * S_LEN + quad * 4;

    float rm = -INFINITY, rZ = 0.f, rZm = 0.f;   // rZ/rZm: per-lane partials
    f32x4 oacc[4];
    const f32x4 zz = {0.f, 0.f, 0.f, 0.f};
    #pragma unroll
    for (int dt = 0; dt < 4; ++dt) oacc[dt] = zz;

    // prologue: stage first tile
    int4 kv0 = *(const int4*)(kg + (size_t)(kBeg + srow) * ldk);
    int4 kv1 = *(const int4*)(kg + (size_t)(kBeg + srow + 32) * ldk);
    int4 vv0 = *(const int4*)(vg + kBeg);
    int4 vv1 = *(const int4*)(vg + 32 * S_LEN + kBeg);
    *(int4*)&Ks[srow * 72 + scol]        = kv0;
    *(int4*)&Ks[(srow + 32) * 72 + scol] = kv1;
    *(int4*)&Vs[srow * 72 + scol]        = vv0;
    *(int4*)&Vs[(srow + 32) * 72 + scol] = vv1;
    __syncthreads();

    for (int k0 = kBeg; k0 < kEnd; k0 += 64) {
        const bool more = (k0 + 64 < kEnd);
        // T14: issue next tile's global loads now; latency hides under compute
        if (more) {
            kv0 = *(const int4*)(kg + (size_t)(k0 + 64 + srow) * ldk);
            kv1 = *(const int4*)(kg + (size_t)(k0 + 64 + srow + 32) * ldk);
            vv0 = *(const int4*)(vg + k0 + 64);
            vv1 = *(const int4*)(vg + 32 * S_LEN + k0 + 64);
        }
        float4 m4[4];
        #pragma unroll
        for (int jt = 0; jt < 4; ++jt)
            m4[jt] = *(const float4*)(mrow + k0 + jt * 16);

        // QK^T from LDS K
        f32x4 sacc[4];
        #pragma unroll
        for (int jt = 0; jt < 4; ++jt) sacc[jt] = zz;
        __builtin_amdgcn_s_setprio(1);
        #pragma unroll
        for (int jt = 0; jt < 4; ++jt) {
            bf16x8 kf0 = *(const bf16x8*)&Ks[(jt * 16 + l15) * 72 + quad * 8];
            bf16x8 kf1 = *(const bf16x8*)&Ks[(jt * 16 + l15) * 72 + 32 + quad * 8];
            sacc[jt] = __builtin_amdgcn_mfma_f32_16x16x32_bf16(kf0, qf[0], sacc[jt], 0, 0, 0);
            sacc[jt] = __builtin_amdgcn_mfma_f32_16x16x32_bf16(kf1, qf[1], sacc[jt], 0, 0, 0);
        }
        __builtin_amdgcn_s_setprio(0);

        // masked scores + tree row-max (log2 domain)
        float mxj[4];
        #pragma unroll
        for (int jt = 0; jt < 4; ++jt) {
            float mm[4] = {m4[jt].x, m4[jt].y, m4[jt].z, m4[jt].w};
            #pragma unroll
            for (int r = 0; r < 4; ++r)
                sacc[jt][r] = sacc[jt][r] * mm[r];
            mxj[jt] = fmaxf(fmaxf(sacc[jt][0], sacc[jt][1]),
                            fmaxf(sacc[jt][2], sacc[jt][3]));
        }
        float mx = fmaxf(fmaxf(mxj[0], mxj[1]), fmaxf(mxj[2], mxj[3]));
        mx = fmaxf(mx, __shfl_xor(mx, 16));
        mx = fmaxf(mx, __shfl_xor(mx, 32));
        // T13 defer-max: only rescale when the running max actually grows >8
        if (!__all(mx <= rm + 8.0f)) {
            float mn = fmaxf(rm, mx);
            float al = __builtin_amdgcn_exp2f(rm - mn);
            rm = mn; rZ *= al; rZm *= al;
            #pragma unroll
            for (int dt = 0; dt < 4; ++dt)
                #pragma unroll
                for (int r = 0; r < 4; ++r) oacc[dt][r] *= al;
        }

        // P = exp2(s - rm); per-lane z/zm accumulation (no shfl here)
        float z = 0.f, zm = 0.f;
        #pragma unroll
        for (int jt = 0; jt < 4; ++jt) {
            float mm[4] = {m4[jt].x, m4[jt].y, m4[jt].z, m4[jt].w};
            float pv[4];
            #pragma unroll
            for (int r = 0; r < 4; ++r) {
                float e = __builtin_amdgcn_exp2f(sacc[jt][r] - rm);
                float pm = e * mm[r];
                z += e; zm += pm; pv[r] = pm;
            }
            unsigned lo, hi;
            asm("v_cvt_pk_bf16_f32 %0, %1, %2" : "=v"(lo) : "v"(pv[0]), "v"(pv[1]));
            asm("v_cvt_pk_bf16_f32 %0, %1, %2" : "=v"(hi) : "v"(pv[2]), "v"(pv[3]));
            uint2 pk; pk.x = lo; pk.y = hi;
            *(uint2*)&Ps[l15 * 72 + jt * 16 + quad * 4] = pk;
        }
        rZ += z; rZm += zm;

        // PV from LDS V; P from per-wave LDS (no cross-wave sync needed)
        bf16x8 pf0 = *(const bf16x8*)&Ps[l15 * 72 + quad * 8];
        bf16x8 pf1 = *(const bf16x8*)&Ps[l15 * 72 + 32 + quad * 8];
        __builtin_amdgcn_s_setprio(1);
        #pragma unroll
        for (int dt = 0; dt < 4; ++dt) {
            bf16x8 vf0 = *(const bf16x8*)&Vs[(dt * 16 + l15) * 72 + quad * 8];
            bf16x8 vf1 = *(const bf16x8*)&Vs[(dt * 16 + l15) * 72 + 32 + quad * 8];
            oacc[dt] = __builtin_amdgcn_mfma_f32_16x16x32_bf16(vf0, pf0, oacc[dt], 0, 0, 0);
            oacc[dt] = __builtin_amdgcn_mfma_f32_16x16x32_bf16(vf1, pf1, oacc[dt], 0, 0, 0);
        }
        __builtin_amdgcn_s_setprio(0);

        // commit prefetched tile to LDS
        if (more) {
            __syncthreads();
            *(int4*)&Ks[srow * 72 + scol]        = kv0;
            *(int4*)&Ks[(srow + 32) * 72 + scol] = kv1;
            *(int4*)&Vs[srow * 72 + scol]        = vv0;
            *(int4*)&Vs[(srow + 32) * 72 + scol] = vv1;
            __syncthreads();
        }
    }

    // deferred z/zm cross-lane reduction (once instead of per-tile)
    rZ  += __shfl_xor(rZ, 16);  rZ  += __shfl_xor(rZ, 32);
    rZm += __shfl_xor(rZm, 16); rZm += __shfl_xor(rZm, 32);

    unsigned short* op = Opart + (((size_t)(p * 16 + bh) * S_LEN + iRow) * 64);
    #pragma unroll
    for (int dt = 0; dt < 4; ++dt) {
        unsigned lo, hi;
        asm("v_cvt_pk_bf16_f32 %0, %1, %2" : "=v"(lo) : "v"(oacc[dt][0]), "v"(oacc[dt][1]));
        asm("v_cvt_pk_bf16_f32 %0, %1, %2" : "=v"(hi) : "v"(oacc[dt][2]), "v"(oacc[dt][3]));
        uint2 o2; o2.x = lo; o2.y = hi;
        *(uint2*)(op + dt * 16 + quad * 4) = o2;
    }
    if (quad == 0) {
        float4 st; st.x = rm; st.y = rZ; st.z = rZm; st.w = 0.f;
        *(float4*)&stats[(((size_t)p * 16 + bh) * S_LEN + iRow) * 4] = st;
    }
}

// ---------------- combine the two split-K partials ----------------
// NOTE: stats.x (running max) is in log2 units -> exp2 here.
__global__ __launch_bounds__(256) void attn_combine(
    const unsigned short* __restrict__ Opart, const float* __restrict__ stats,
    unsigned short* __restrict__ O)
{
    const int bh = blockIdx.y, b = bh >> 3, h = bh & 7;
    const int q0 = blockIdx.x * 64;
    const int tid = threadIdx.x;
    const int i = tid >> 2, dq = (tid & 3) * 16;
    const int qg = q0 + i;

    float4 s0 = *(const float4*)&stats[(((size_t)0 * 16 + bh) * S_LEN + qg) * 4];
    float4 s1 = *(const float4*)&stats[(((size_t)1 * 16 + bh) * S_LEN + qg) * 4];
    float ms = fmaxf(s0.x, s1.x);
    float w0 = __builtin_amdgcn_exp2f(s0.x - ms), w1 = __builtin_amdgcn_exp2f(s1.x - ms);
    float Z  = w0 * s0.y + w1 * s1.y;
    float Zm = w0 * s0.z + w1 * s1.z;
    float inv = 1.0f / (Zm + 1e-8f * Z);
    w0 *= inv; w1 *= inv;

    const unsigned short* p0 = Opart + (((size_t)0 * 16 + bh) * S_LEN + qg) * 64 + dq;
    const unsigned short* p1 = Opart + (((size_t)1 * 16 + bh) * S_LEN + qg) * 64 + dq;
    union { int4 v; unsigned short u[8]; } a0, a1, r;
    unsigned short* dst = O + (size_t)(b * S_LEN + qg) * DMODEL + h * HDIM + dq;
    #pragma unroll
    for (int half = 0; half < 2; ++half) {
        a0.v = *(const int4*)(p0 + half * 8);
        a1.v = *(const int4*)(p1 + half * 8);
        #pragma unroll
        for (int e = 0; e < 8; ++e)
            r.u[e] = f2bf(w0 * bf2f(a0.u[e]) + w1 * bf2f(a1.u[e]));
        *(int4*)(dst + half * 8) = r.v;
    }
}

// ---------------- launch ----------------
extern "C" void kernel_launch(void* const* d_in, const int* in_sizes, int n_in,
                              void* d_out, int out_size, void* d_ws, size_t ws_size,
                              hipStream_t stream)
{
    const float* gene_emb = (const float*)d_in[0];
    const float* expr_emb = (const float*)d_in[1];
    const float* M        = (const float*)d_in[2];
    const float* g_wq = (const float*)d_in[3];
    const float* g_wk = (const float*)d_in[4];
    const float* g_wv = (const float*)d_in[5];
    const float* g_wo = (const float*)d_in[6];
    const float* g_bq = (const float*)d_in[7];
    const float* g_bk = (const float*)d_in[8];
    const float* g_bv = (const float*)d_in[9];
    const float* g_bo = (const float*)d_in[10];
    const float* e_wf = (const float*)d_in[11];
    const float* e_bf = (const float*)d_in[12];
    const float* e_wq = (const float*)d_in[13];
    const float* e_wk = (const float*)d_in[14];
    const float* e_wv = (const float*)d_in[15];
    const float* e_wo = (const float*)d_in[16];
    const float* e_bq = (const float*)d_in[17];
    const float* e_bk = (const float*)d_in[18];
    const float* e_bv = (const float*)d_in[19];
    const float* e_bo = (const float*)d_in[20];
    const float* ln_g1_w = (const float*)d_in[21];
    const float* ln_g2_w = (const float*)d_in[22];
    const float* ln_e1_w = (const float*)d_in[23];
    const float* ln_e2_w = (const float*)d_in[24];
    const float* ln_g1_b = (const float*)d_in[25];
    const float* ln_g2_b = (const float*)d_in[26];
    const float* ln_e1_b = (const float*)d_in[27];
    const float* ln_e2_b = (const float*)d_in[28];
    const float* fg_w1 = (const float*)d_in[29];
    const float* fg_b1 = (const float*)d_in[30];
    const float* fg_w2 = (const float*)d_in[31];
    const float* fg_b2 = (const float*)d_in[32];
    const float* fe_w1 = (const float*)d_in[33];
    const float* fe_b1 = (const float*)d_in[34];
    const float* fe_w2 = (const float*)d_in[35];
    const float* fe_b2 = (const float*)d_in[36];

    float* out_gene = (float*)d_out;
    float* out_expr = out_gene + (size_t)NROWS * DMODEL;

    // ---- workspace (MB offsets), round-6 proven aliasing ----
    char* ws = (char*)d_ws;
    const size_t MB1 = 1024 * 1024;
    unsigned short* bufA16  = (unsigned short*)(ws + 0 * MB1);   // 0-4
    unsigned short* bufAt16 = (unsigned short*)(ws + 4 * MB1);   // 4-8 attn combined
    unsigned short* bufQKV  = (unsigned short*)(ws + 8 * MB1);   // 8-20 gene [4096][1536]
    unsigned short* bufQKe  = (unsigned short*)(ws + 8 * MB1);   // 8-16 expr [4096][1024]
    unsigned short* bufV16  = (unsigned short*)(ws + 16 * MB1);  // 16-20 expr V
    unsigned short* bufVt   = (unsigned short*)(ws + 20 * MB1);  // 20-24
    unsigned short* bufCat  = (unsigned short*)(ws + 24 * MB1);  // 24-32 expr concat (dead pre-attn)
    unsigned short* bufOp   = (unsigned short*)(ws + 24 * MB1);  // 24-32 attn O partials
    float*          bufSt   = (float*)(ws + 32 * MB1);           // 32-33 attn stats
    float*          bufX    = (float*)(ws + 33 * MB1);           // 33-41 fp32 residual
    unsigned short* bufH16  = (unsigned short*)(ws + 8 * MB1);   // 8-24 FFN hidden
    char* wp = ws + 41 * MB1;
    unsigned short* sq8    = (unsigned short*)wp;                 // 8 x 512x512
    unsigned short* gwq_t  = sq8 + 0 * 512 * 512;
    unsigned short* gwo_t  = sq8 + 3 * 512 * 512;
    unsigned short* ewq_t  = sq8 + 4 * 512 * 512;
    unsigned short* ewv_t  = sq8 + 6 * 512 * 512;
    unsigned short* ewo_t  = sq8 + 7 * 512 * 512;
    unsigned short* ewf_t  = sq8 + 8 * 512 * 512;                 // 1024x512
    unsigned short* ffn1   = ewf_t + 1024 * 512;                  // 2 x [2048][512]
    unsigned short* fgw1_t = ffn1;
    unsigned short* few1_t = ffn1 + 512 * 2048;
    unsigned short* ffn2   = few1_t + 512 * 2048;                 // 2 x [512][2048]
    unsigned short* fgw2_t = ffn2;
    unsigned short* few2_t = ffn2 + 2048 * 512;
    float* biasg = (float*)(few2_t + 2048 * 512);
    float* biase = biasg + 1536;

    dim3 blk(256);
    dim3 blk512(512);
    dim3 ln_grid(NROWS);
    dim3 g512s(8, 64);    // 64x64 tiles, Mo=512 -> 512 blocks (2 blocks/CU)
    dim3 g1024(8, 32);
    dim3 g1536(12, 32);
    dim3 g2048(16, 32);
    dim3 attn_grid(S_LEN / 64, 16, 2);
    dim3 comb_grid(S_LEN / 64, 16);
    dim3 vt_grid(S_LEN / 64, NHEAD, 2);

    // ---- ALL weight prep: one launch ----
    prep_all<<<dim3(6666), blk, 0, stream>>>(
        g_wq, g_wk, g_wv, g_wo, e_wq, e_wk, e_wv, e_wo,
        e_wf, fg_w1, fe_w1, fg_w2, fe_w2,
        g_bq, g_bk, g_bv, e_bq, e_bk,
        sq8, biasg, biase);

    // ---------------- gene branch ----------------
    ln_kernel<<<ln_grid, blk, 0, stream>>>(gene_emb, ln_g1_w, ln_g1_b, bufA16, 512);
    gemm_mfma<<<g1536, blk512, 0, stream>>>(bufA16, 512, gwq_t, biasg, nullptr, nullptr, nullptr, bufQKV, 512, 1536, 0);
    vtrans<<<vt_grid, blk, 0, stream>>>(bufQKV + 1024, 1536, bufVt);
    attn_mfma_split<<<attn_grid, blk, 0, stream>>>(bufQKV, 1536, bufQKV + 512, 1536, bufVt, M, bufOp, bufSt);
    attn_combine<<<comb_grid, blk, 0, stream>>>(bufOp, bufSt, bufAt16);
    gemm_mfma64<<<g512s, blk512, 0, stream>>>(bufAt16, 512, gwo_t, g_bo, gene_emb, nullptr, bufX, nullptr, 512, 512, 0);
    ln_kernel<<<ln_grid, blk, 0, stream>>>(bufX, ln_g2_w, ln_g2_b, bufA16, 512);
    gemm_mfma<<<g2048, blk512, 0, stream>>>(bufA16, 512, fgw1_t, fg_b1, nullptr, nullptr, nullptr, bufH16, 512, 2048, 1);
    gemm_mfma64<<<g512s, blk512, 0, stream>>>(bufH16, 2048, fgw2_t, fg_b2, bufX, bufA16, out_gene, nullptr, 2048, 512, 0);

    // ---------------- expr branch ----------------
    ln_cat_kernel<<<ln_grid, blk, 0, stream>>>(gene_emb, expr_emb, ln_e1_w, ln_e1_b, bufCat);
    gemm_mfma64<<<g512s, blk512, 0, stream>>>(bufCat, 1024, ewf_t, e_bf, nullptr, nullptr, nullptr, bufA16, 1024, 512, 0);
    gemm_mfma<<<g1024, blk512, 0, stream>>>(bufA16, 512, ewq_t, biase, nullptr, nullptr, nullptr, bufQKe, 512, 1024, 0);
    gemm_mfma64<<<g512s, blk512, 0, stream>>>(bufCat + 512, 1024, ewv_t, e_bv, nullptr, nullptr, nullptr, bufV16, 512, 512, 0);
    vtrans<<<vt_grid, blk, 0, stream>>>(bufV16, 512, bufVt);
    attn_mfma_split<<<attn_grid, blk, 0, stream>>>(bufQKe, 1024, bufQKe + 512, 1024, bufVt, M, bufOp, bufSt);
    attn_combine<<<comb_grid, blk, 0, stream>>>(bufOp, bufSt, bufAt16);
    gemm_mfma64<<<g512s, blk512, 0, stream>>>(bufAt16, 512, ewo_t, e_bo, expr_emb, nullptr, bufX, nullptr, 512, 512, 0);
    ln_kernel<<<ln_grid, blk, 0, stream>>>(bufX, ln_e2_w, ln_e2_b, bufA16, 512);
    gemm_mfma<<<g2048, blk512, 0, stream>>>(bufA16, 512, few1_t, fe_b1, nullptr, nullptr, nullptr, bufH16, 512, 2048, 1);
    gemm_mfma64<<<g512s, blk512, 0, stream>>>(bufH16, 2048, few2_t, fe_b2, bufX, bufA16, out_expr, nullptr, 2048, 512, 0);
}